// Round 3
// baseline (61181.616 us; speedup 1.0000x reference)
//
#include <hip/hip_runtime.h>

typedef unsigned int   u32;
typedef unsigned short u16;
typedef float  f32x4  __attribute__((ext_vector_type(4)));
typedef __bf16 bf16x8 __attribute__((ext_vector_type(8)));
static_assert(sizeof(bf16x8) == 16, "bf16x8 must be 16B");

#define DEV static __device__ __forceinline__

constexpr int BN = 64;     // batch
constexpr int TN = 128;    // time steps
constexpr int DN = 256;    // input/latent dim
constexpr int HN = 1024;   // hidden
constexpr int NWG = 64;    // persistent workgroups
constexpr size_t BTD = (size_t)BN * TN * DN;   // 2097152

// ---------- bf16 helpers (RNE) ----------
DEV u16 f2b(float f) {
    u32 u = __builtin_bit_cast(u32, f);
    u += 0x7fffu + ((u >> 16) & 1u);
    return (u16)(u >> 16);
}
DEV float b2f(u16 h) { u32 u = ((u32)h) << 16; return __builtin_bit_cast(float, u); }
DEV void split2(float v, u16 &hi, u16 &lo) { u16 h = f2b(v); hi = h; lo = f2b(v - b2f(h)); }
DEV bf16x8 ldfrag(const u16 *p) { return __builtin_bit_cast(bf16x8, *reinterpret_cast<const uint4 *>(p)); }
DEV float sigm(float x) { return 1.0f / (1.0f + __expf(-x)); }
#define MFMA16(a, b, c) __builtin_amdgcn_mfma_f32_16x16x32_bf16((a), (b), (c), 0, 0, 0)

// ---------- grid barrier (device-scope, cross-XCD safe) ----------
// Monotonic counter: barrier k waits for counter >= k*NWG. Release fence
// (wbl2) before arrival; relaxed agent-scope polls (NO per-poll invalidate);
// one acquire fence (buffer_inv) after exit.
DEV void grid_barrier(u32 *bar, u32 target) {
    __syncthreads();                       // all WG stores issued+drained (vmcnt0 before s_barrier)
    if (threadIdx.x == 0) {
        __threadfence();                   // release: push L2 to coherence point
        __hip_atomic_fetch_add(bar, 1u, __ATOMIC_RELAXED, __HIP_MEMORY_SCOPE_AGENT);
        while (__hip_atomic_load(bar, __ATOMIC_RELAXED, __HIP_MEMORY_SCOPE_AGENT) < target)
            __builtin_amdgcn_s_sleep(2);
        __threadfence();                   // acquire: invalidate stale L1/L2
    }
    __syncthreads();
}

// ---------- zero scratch ----------
__global__ void zero_ws(uint4 *p, size_t n16) {
    size_t i = (size_t)blockIdx.x * blockDim.x + threadIdx.x;
    size_t st = (size_t)gridDim.x * blockDim.x;
    uint4 z; z.x = z.y = z.z = z.w = 0u;
    for (; i < n16; i += st) p[i] = z;
}

// ---------- prep t=0 encoder input (x_0 and x_hat_0 = x_0 - 0.5) ----------
__global__ void prep_x0(const float *__restrict__ x, u16 *__restrict__ ahi, u16 *__restrict__ alo) {
    int idx = blockIdx.x * 256 + threadIdx.x;          // 64*256 = 16384
    int row = idx >> 8, col = idx & 255;
    float xv = x[((size_t)row * TN) * DN + col];       // x[row][0][col]
    float xh = xv - 0.5f;                              // x0 - sigmoid(0)
    u16 h, l;
    split2(xv, h, l); ahi[row * 1536 + col] = h;        alo[row * 1536 + col] = l;
    split2(xh, h, l); ahi[row * 1536 + 256 + col] = h;  alo[row * 1536 + 256 + col] = l;
}

// ---------- pack fp32 weights -> bf16 hi/lo in MFMA fragment order ----------
// packed elem (n',k): nt=n'>>4, nl=n'&15, kt=k>>5, ko=k&31 ; lane=nl+16*(ko>>3)
// idx = ((nt*KTILES + kt)*64 + lane)*8 + (ko&7)
// mode 0: n'=n ; mode 1 (LSTM gate perm, n=g*1024+j): n'=(j>>4)*64+g*16+(j&15)
// mode 2 (W_mu):  n'=(n>>5)*64+(n&31) ; mode 3 (W_logvar): n'=(n>>5)*64+32+(n&31)
__global__ void pack_w(const float *__restrict__ src, u16 *__restrict__ dhi, u16 *__restrict__ dlo,
                       int Nsrc, int Ksrc, int koff, int ktiles, int mode) {
    int idx = blockIdx.x * 256 + threadIdx.x;
    if (idx >= Nsrc * Ksrc) return;
    int n = idx / Ksrc, k = idx - n * Ksrc;
    float v = src[idx];
    int np;
    if (mode == 1)      { int g = n >> 10, j = n & 1023; np = ((j >> 4) << 6) + (g << 4) + (j & 15); }
    else if (mode == 2) { np = ((n >> 5) << 6) + (n & 31); }
    else if (mode == 3) { np = ((n >> 5) << 6) + 32 + (n & 31); }
    else                { np = n; }
    int kk = koff + k;
    int nt = np >> 4, nl = np & 15, kt = kk >> 5, ko = kk & 31;
    int ln = nl + ((ko >> 3) << 4);
    size_t o = (((size_t)nt * ktiles + kt) * 64 + ln) * 8 + (ko & 7);
    u16 hi = f2b(v);
    u16 lo = f2b(v - b2f(hi));
    dhi[o] = hi; dlo[o] = lo;
}

// ---------- one LSTM layer step (device body; 64 WGs x 512 thr) ----------
// WG owns 16 h-cols (all 4 gates). wave = mh*4+gate; 2 MFMA row-tiles.
// hi/lo split: acc += Ah*Bh + Ah*Bl + Al*Bh
template <int KTILES>
DEV void lstm_body(const u16 *__restrict__ Ahi, const u16 *__restrict__ Alo,
                   const u16 *__restrict__ Whi, const u16 *__restrict__ Wlo,
                   const float *__restrict__ bias, float *__restrict__ cbuf,
                   u16 *__restrict__ d0hi, u16 *__restrict__ d0lo, int s0,
                   u16 *__restrict__ d1hi, u16 *__restrict__ d1lo, int s1,
                   float (*gl)[64][16]) {
    constexpr int KTOT = KTILES * 32;
    const int wg = blockIdx.x;
    const int tid = threadIdx.x;
    const int wave = tid >> 6, lane = tid & 63;
    const int gate = wave & 3, mh = wave >> 2;
    const int r16 = lane & 15, kg = (lane >> 4) << 3;
    const int ntile = (wg << 2) + gate;

    const u16 *ah = Ahi + (((mh << 5) + r16) * KTOT + kg);
    const u16 *al = Alo + (((mh << 5) + r16) * KTOT + kg);
    const u16 *wh = Whi + ((size_t)ntile * KTILES) * 512 + (lane << 3);
    const u16 *wl = Wlo + ((size_t)ntile * KTILES) * 512 + (lane << 3);

    f32x4 acc0 = {0.f, 0.f, 0.f, 0.f}, acc1 = {0.f, 0.f, 0.f, 0.f};
    #pragma unroll 4
    for (int kt = 0; kt < KTILES; ++kt) {
        bf16x8 bh  = ldfrag(wh + (kt << 9));
        bf16x8 bl  = ldfrag(wl + (kt << 9));
        bf16x8 a0h = ldfrag(ah + (kt << 5));
        bf16x8 a1h = ldfrag(ah + 16 * KTOT + (kt << 5));
        bf16x8 a0l = ldfrag(al + (kt << 5));
        bf16x8 a1l = ldfrag(al + 16 * KTOT + (kt << 5));
        acc0 = MFMA16(a0h, bh, acc0);
        acc1 = MFMA16(a1h, bh, acc1);
        acc0 = MFMA16(a0h, bl, acc0);
        acc1 = MFMA16(a1h, bl, acc1);
        acc0 = MFMA16(a0l, bh, acc0);
        acc1 = MFMA16(a1l, bh, acc1);
    }

    const int hcol = (wg << 4) + r16;
    const float bv = bias[(gate << 10) + hcol];
    #pragma unroll
    for (int j = 0; j < 4; ++j) {
        int r0 = (mh << 5) + ((lane >> 4) << 2) + j;
        float v0 = acc0[j] + bv, v1 = acc1[j] + bv;
        if (gate == 2) { v0 = tanhf(v0); v1 = tanhf(v1); }
        else           { v0 = sigm(v0);  v1 = sigm(v1); }
        gl[gate][r0][r16]      = v0;
        gl[gate][r0 + 16][r16] = v1;
    }
    __syncthreads();

    #pragma unroll
    for (int e = tid; e < 1024; e += 512) {
        int row = e >> 4, col = e & 15;
        int hc = (wg << 4) + col;
        float iv = gl[0][row][col], fv = gl[1][row][col];
        float gv = gl[2][row][col], ov = gl[3][row][col];
        float cn = fv * cbuf[row * HN + hc] + iv * gv;
        cbuf[row * HN + hc] = cn;
        float h = ov * tanhf(cn);
        u16 hh, hl; split2(h, hh, hl);
        size_t o0 = (size_t)row * s0 + hc;
        size_t o1 = (size_t)row * s1 + hc;
        d0hi[o0] = hh; d0lo[o0] = hl;
        d1hi[o1] = hh; d1lo[o1] = hl;
    }
}

// ---------- mu / logvar / z (wg < 8 only) ----------
DEV void z_body(const u16 *__restrict__ Ahi, const u16 *__restrict__ Alo,
                const u16 *__restrict__ Whi, const u16 *__restrict__ Wlo,
                const float *__restrict__ bmu, const float *__restrict__ blv,
                const float *__restrict__ eps, int t,
                float *__restrict__ out, u16 *__restrict__ zhi, u16 *__restrict__ zlo, int sz,
                float (*gl)[64][16]) {
    constexpr int KTILES = 32, KTOT = 1024;
    const int wg = blockIdx.x;
    const int tid = threadIdx.x;
    const int wave = tid >> 6, lane = tid & 63;
    const int sub = wave & 3, mh = wave >> 2;
    const int r16 = lane & 15, kg = (lane >> 4) << 3;
    const int ntile = (wg << 2) + sub;

    const u16 *ah = Ahi + (((mh << 5) + r16) * KTOT + kg);
    const u16 *al = Alo + (((mh << 5) + r16) * KTOT + kg);
    const u16 *wh = Whi + ((size_t)ntile * KTILES) * 512 + (lane << 3);
    const u16 *wl = Wlo + ((size_t)ntile * KTILES) * 512 + (lane << 3);

    f32x4 acc0 = {0.f, 0.f, 0.f, 0.f}, acc1 = {0.f, 0.f, 0.f, 0.f};
    #pragma unroll 4
    for (int kt = 0; kt < KTILES; ++kt) {
        bf16x8 bh  = ldfrag(wh + (kt << 9));
        bf16x8 bl  = ldfrag(wl + (kt << 9));
        bf16x8 a0h = ldfrag(ah + (kt << 5));
        bf16x8 a1h = ldfrag(ah + 16 * KTOT + (kt << 5));
        bf16x8 a0l = ldfrag(al + (kt << 5));
        bf16x8 a1l = ldfrag(al + 16 * KTOT + (kt << 5));
        acc0 = MFMA16(a0h, bh, acc0);
        acc1 = MFMA16(a1h, bh, acc1);
        acc0 = MFMA16(a0h, bl, acc0);
        acc1 = MFMA16(a1h, bl, acc1);
        acc0 = MFMA16(a0l, bh, acc0);
        acc1 = MFMA16(a1l, bh, acc1);
    }

    const int dcol0 = (wg << 5) + ((sub & 1) << 4) + r16;
    const float bv = (sub < 2) ? bmu[dcol0] : blv[dcol0];
    #pragma unroll
    for (int j = 0; j < 4; ++j) {
        int r0 = (mh << 5) + ((lane >> 4) << 2) + j;
        float v0 = fminf(20.f, fmaxf(-20.f, acc0[j] + bv));
        float v1 = fminf(20.f, fmaxf(-20.f, acc1[j] + bv));
        gl[sub][r0][r16]      = v0;
        gl[sub][r0 + 16][r16] = v1;
    }
    __syncthreads();

    #pragma unroll
    for (int e = tid; e < 2048; e += 512) {
        int row = e >> 5, c5 = e & 31;
        int cs = c5 >> 4, cl = c5 & 15;
        float mu = gl[cs][row][cl];
        float lv = gl[2 + cs][row][cl];
        int dcol = (wg << 5) + c5;
        size_t po = ((size_t)row * TN + t) * DN + dcol;
        float ev = eps[po];
        float sd = expf(0.5f * lv);
        float z = mu + ev * sd;
        out[2 * BTD + po] = mu;
        out[3 * BTD + po] = lv;
        out[4 * BTD + po] = z;
        u16 zh, zl; split2(z, zh, zl);
        zhi[(size_t)row * sz + dcol] = zh;
        zlo[(size_t)row * sz + dcol] = zl;
    }
}

// ---------- logits / rec / next-step encoder input (wg < 4 only) ----------
DEV void out_body(const u16 *__restrict__ Ahi, const u16 *__restrict__ Alo,
                  const u16 *__restrict__ Whi, const u16 *__restrict__ Wlo,
                  const float *__restrict__ bout, const float *__restrict__ x, int t,
                  float *__restrict__ out, u16 *__restrict__ e0hi, u16 *__restrict__ e0lo) {
    constexpr int KTILES = 32, KTOT = 1024;
    const int wg = blockIdx.x;
    const int tid = threadIdx.x;
    const int wave = tid >> 6, lane = tid & 63;
    const int sub = wave & 3, mh = wave >> 2;
    const int r16 = lane & 15, kg = (lane >> 4) << 3;
    const int ntile = (wg << 2) + sub;

    const u16 *ah = Ahi + (((mh << 5) + r16) * KTOT + kg);
    const u16 *al = Alo + (((mh << 5) + r16) * KTOT + kg);
    const u16 *wh = Whi + ((size_t)ntile * KTILES) * 512 + (lane << 3);
    const u16 *wl = Wlo + ((size_t)ntile * KTILES) * 512 + (lane << 3);

    f32x4 acc0 = {0.f, 0.f, 0.f, 0.f}, acc1 = {0.f, 0.f, 0.f, 0.f};
    #pragma unroll 4
    for (int kt = 0; kt < KTILES; ++kt) {
        bf16x8 bh  = ldfrag(wh + (kt << 9));
        bf16x8 bl  = ldfrag(wl + (kt << 9));
        bf16x8 a0h = ldfrag(ah + (kt << 5));
        bf16x8 a1h = ldfrag(ah + 16 * KTOT + (kt << 5));
        bf16x8 a0l = ldfrag(al + (kt << 5));
        bf16x8 a1l = ldfrag(al + 16 * KTOT + (kt << 5));
        acc0 = MFMA16(a0h, bh, acc0);
        acc1 = MFMA16(a1h, bh, acc1);
        acc0 = MFMA16(a0h, bl, acc0);
        acc1 = MFMA16(a1h, bl, acc1);
        acc0 = MFMA16(a0l, bh, acc0);
        acc1 = MFMA16(a1l, bh, acc1);
    }

    const int dcol = (wg << 6) + (sub << 4) + r16;
    const float bv = bout[dcol];
    #pragma unroll
    for (int j = 0; j < 4; ++j) {
        int r0 = (mh << 5) + ((lane >> 4) << 2) + j;
        #pragma unroll
        for (int half = 0; half < 2; ++half) {
            int r = r0 + half * 16;
            float lg = (half ? acc1[j] : acc0[j]) + bv;
            float rc = sigm(lg);
            size_t po = ((size_t)r * TN + t) * DN + dcol;
            out[po] = rc;
            out[BTD + po] = lg;
            if (t + 1 < TN) {
                float xv = x[((size_t)r * TN + t + 1) * DN + dcol];
                float xh = xv - rc;
                u16 h, l;
                split2(xv, h, l);
                e0hi[r * 1536 + dcol] = h;       e0lo[r * 1536 + dcol] = l;
                split2(xh, h, l);
                e0hi[r * 1536 + 256 + dcol] = h; e0lo[r * 1536 + 256 + dcol] = l;
            }
        }
    }
}

// ---------- persistent all-timesteps kernel ----------
struct Params {
    const float *x, *eps;
    const float *eb, *db, *bmu, *blv, *bout;
    const u16 *Pe0h, *Pe0l, *Pe1h, *Pe1l, *Pe2h, *Pe2l;
    const u16 *Pd0h, *Pd0l, *Pd1h, *Pd1l, *Pd2h, *Pd2l;
    const u16 *Pzh, *Pzl, *Poh, *Pol;
    u16 *Ae0, *Ae1, *Ae2, *Ad0, *Ad1, *Ad2, *Az, *Ao;
    float *ce0, *ce1, *ce2, *cd0, *cd1, *cd2;
    float *out;
    u32 *bar;
};

DEV u16 *AHd(u16 *b, int W, int par) { return b + (size_t)(par * 2 + 0) * 64 * W; }
DEV u16 *ALd(u16 *b, int W, int par) { return b + (size_t)(par * 2 + 1) * 64 * W; }

__global__ __launch_bounds__(512)
void vae_persist(Params pr) {
    __shared__ float gl[4][64][16];
    const int wg = blockIdx.x;
    u32 seq = 0;

    for (int t = 0; t < TN; ++t) {
        const int p = t & 1, q = p ^ 1;

        // encoder L0: A=[x_t | x_hat | h0(t-1)], K=1536
        lstm_body<48>(AHd(pr.Ae0, 1536, p), ALd(pr.Ae0, 1536, p), pr.Pe0h, pr.Pe0l,
                      pr.eb, pr.ce0,
                      AHd(pr.Ae1, 2048, p), ALd(pr.Ae1, 2048, p), 2048,
                      AHd(pr.Ae0, 1536, q) + 512, ALd(pr.Ae0, 1536, q) + 512, 1536, gl);
        ++seq; grid_barrier(pr.bar, seq * NWG);

        // encoder L1
        lstm_body<64>(AHd(pr.Ae1, 2048, p), ALd(pr.Ae1, 2048, p), pr.Pe1h, pr.Pe1l,
                      pr.eb + 4096, pr.ce1,
                      AHd(pr.Ae2, 2048, p), ALd(pr.Ae2, 2048, p), 2048,
                      AHd(pr.Ae1, 2048, q) + 1024, ALd(pr.Ae1, 2048, q) + 1024, 2048, gl);
        ++seq; grid_barrier(pr.bar, seq * NWG);

        // encoder L2
        lstm_body<64>(AHd(pr.Ae2, 2048, p), ALd(pr.Ae2, 2048, p), pr.Pe2h, pr.Pe2l,
                      pr.eb + 8192, pr.ce2,
                      AHd(pr.Az, 1024, p), ALd(pr.Az, 1024, p), 1024,
                      AHd(pr.Ae2, 2048, q) + 1024, ALd(pr.Ae2, 2048, q) + 1024, 2048, gl);
        ++seq; grid_barrier(pr.bar, seq * NWG);

        // mu / logvar / z
        if (wg < 8)
            z_body(AHd(pr.Az, 1024, p), ALd(pr.Az, 1024, p), pr.Pzh, pr.Pzl,
                   pr.bmu, pr.blv, pr.eps, t, pr.out,
                   AHd(pr.Ad0, 1280, p), ALd(pr.Ad0, 1280, p), 1280, gl);
        ++seq; grid_barrier(pr.bar, seq * NWG);

        // decoder L0: A=[z | h_d0(t-1)], K=1280
        lstm_body<40>(AHd(pr.Ad0, 1280, p), ALd(pr.Ad0, 1280, p), pr.Pd0h, pr.Pd0l,
                      pr.db, pr.cd0,
                      AHd(pr.Ad1, 2048, p), ALd(pr.Ad1, 2048, p), 2048,
                      AHd(pr.Ad0, 1280, q) + 256, ALd(pr.Ad0, 1280, q) + 256, 1280, gl);
        ++seq; grid_barrier(pr.bar, seq * NWG);

        // decoder L1
        lstm_body<64>(AHd(pr.Ad1, 2048, p), ALd(pr.Ad1, 2048, p), pr.Pd1h, pr.Pd1l,
                      pr.db + 4096, pr.cd1,
                      AHd(pr.Ad2, 2048, p), ALd(pr.Ad2, 2048, p), 2048,
                      AHd(pr.Ad1, 2048, q) + 1024, ALd(pr.Ad1, 2048, q) + 1024, 2048, gl);
        ++seq; grid_barrier(pr.bar, seq * NWG);

        // decoder L2
        lstm_body<64>(AHd(pr.Ad2, 2048, p), ALd(pr.Ad2, 2048, p), pr.Pd2h, pr.Pd2l,
                      pr.db + 8192, pr.cd2,
                      AHd(pr.Ao, 1024, p), ALd(pr.Ao, 1024, p), 1024,
                      AHd(pr.Ad2, 2048, q) + 1024, ALd(pr.Ad2, 2048, q) + 1024, 2048, gl);
        ++seq; grid_barrier(pr.bar, seq * NWG);

        // logits / rec / next-step enc input
        if (wg < 4)
            out_body(AHd(pr.Ao, 1024, p), ALd(pr.Ao, 1024, p), pr.Poh, pr.Pol,
                     pr.bout, pr.x, t, pr.out,
                     AHd(pr.Ae0, 1536, q), ALd(pr.Ae0, 1536, q));
        ++seq; grid_barrier(pr.bar, seq * NWG);
    }
}

extern "C" void kernel_launch(void *const *d_in, const int *in_sizes, int n_in,
                              void *d_out, int out_size, void *d_ws, size_t ws_size,
                              hipStream_t stream) {
    (void)in_sizes; (void)n_in; (void)out_size;
    const float *x     = (const float *)d_in[0];
    const float *eps   = (const float *)d_in[1];
    const float *eWih0 = (const float *)d_in[2];
    const float *eWih  = (const float *)d_in[3];
    const float *eWhh  = (const float *)d_in[4];
    const float *eb    = (const float *)d_in[5];
    const float *Wmu   = (const float *)d_in[6];
    const float *bmu   = (const float *)d_in[7];
    const float *Wlv   = (const float *)d_in[8];
    const float *blv   = (const float *)d_in[9];
    const float *dWih0 = (const float *)d_in[10];
    const float *dWih  = (const float *)d_in[11];
    const float *dWhh  = (const float *)d_in[12];
    const float *db    = (const float *)d_in[13];
    const float *Wout  = (const float *)d_in[14];
    const float *bout  = (const float *)d_in[15];
    float *out = (float *)d_out;

    char *ws = (char *)d_ws;
    size_t cur = 0;
    auto alloc = [&](size_t bytes) -> char * {
        char *p = ws + cur;
        cur = (cur + bytes + 255) & ~(size_t)255;
        return p;
    };

    // packed weights (hi/lo bf16, MFMA fragment order) — repacked every call
    u16 *Pe0h = (u16 *)alloc((size_t)4096 * 1536 * 2), *Pe0l = (u16 *)alloc((size_t)4096 * 1536 * 2);
    u16 *Pe1h = (u16 *)alloc((size_t)4096 * 2048 * 2), *Pe1l = (u16 *)alloc((size_t)4096 * 2048 * 2);
    u16 *Pe2h = (u16 *)alloc((size_t)4096 * 2048 * 2), *Pe2l = (u16 *)alloc((size_t)4096 * 2048 * 2);
    u16 *Pd0h = (u16 *)alloc((size_t)4096 * 1280 * 2), *Pd0l = (u16 *)alloc((size_t)4096 * 1280 * 2);
    u16 *Pd1h = (u16 *)alloc((size_t)4096 * 2048 * 2), *Pd1l = (u16 *)alloc((size_t)4096 * 2048 * 2);
    u16 *Pd2h = (u16 *)alloc((size_t)4096 * 2048 * 2), *Pd2l = (u16 *)alloc((size_t)4096 * 2048 * 2);
    u16 *Pzh  = (u16 *)alloc((size_t)512 * 1024 * 2),  *Pzl  = (u16 *)alloc((size_t)512 * 1024 * 2);
    u16 *Poh  = (u16 *)alloc((size_t)256 * 1024 * 2),  *Pol  = (u16 *)alloc((size_t)256 * 1024 * 2);

    // activation buffers [parity][plane hi/lo][64][W] + cell state + barrier
    size_t zstart = cur;
    u16 *Ae0 = (u16 *)alloc((size_t)2 * 2 * 64 * 1536 * 2);
    u16 *Ae1 = (u16 *)alloc((size_t)2 * 2 * 64 * 2048 * 2);
    u16 *Ae2 = (u16 *)alloc((size_t)2 * 2 * 64 * 2048 * 2);
    u16 *Ad0 = (u16 *)alloc((size_t)2 * 2 * 64 * 1280 * 2);
    u16 *Ad1 = (u16 *)alloc((size_t)2 * 2 * 64 * 2048 * 2);
    u16 *Ad2 = (u16 *)alloc((size_t)2 * 2 * 64 * 2048 * 2);
    u16 *Az  = (u16 *)alloc((size_t)2 * 2 * 64 * 1024 * 2);
    u16 *Ao  = (u16 *)alloc((size_t)2 * 2 * 64 * 1024 * 2);
    float *cb = (float *)alloc((size_t)6 * 64 * 1024 * 4);
    u32 *bar = (u32 *)alloc(256);
    size_t zend = cur;
    if (ws_size < cur) return;   // scratch too small -> bail

    // init: zero activations/c/barrier, write t=0 encoder input
    zero_ws<<<2048, 256, 0, stream>>>((uint4 *)(ws + zstart), (zend - zstart) / 16);
    prep_x0<<<64, 256, 0, stream>>>(x, Ae0, Ae0 + (size_t)2 * 64 * 1536);

    auto PK = [&](const float *src, u16 *dh, u16 *dl, int N, int K, int koff, int kt, int mode) {
        int n = N * K;
        pack_w<<<(n + 255) / 256, 256, 0, stream>>>(src, dh, dl, N, K, koff, kt, mode);
    };
    const size_t WSTEP = (size_t)4096 * 1024;
    PK(eWih0, Pe0h, Pe0l, 4096, 512, 0, 48, 1);
    PK(eWhh,  Pe0h, Pe0l, 4096, 1024, 512, 48, 1);
    PK(eWih,  Pe1h, Pe1l, 4096, 1024, 0, 64, 1);
    PK(eWhh + WSTEP, Pe1h, Pe1l, 4096, 1024, 1024, 64, 1);
    PK(eWih + WSTEP, Pe2h, Pe2l, 4096, 1024, 0, 64, 1);
    PK(eWhh + 2 * WSTEP, Pe2h, Pe2l, 4096, 1024, 1024, 64, 1);
    PK(dWih0, Pd0h, Pd0l, 4096, 256, 0, 40, 1);
    PK(dWhh,  Pd0h, Pd0l, 4096, 1024, 256, 40, 1);
    PK(dWih,  Pd1h, Pd1l, 4096, 1024, 0, 64, 1);
    PK(dWhh + WSTEP, Pd1h, Pd1l, 4096, 1024, 1024, 64, 1);
    PK(dWih + WSTEP, Pd2h, Pd2l, 4096, 1024, 0, 64, 1);
    PK(dWhh + 2 * WSTEP, Pd2h, Pd2l, 4096, 1024, 1024, 64, 1);
    PK(Wmu, Pzh, Pzl, 256, 1024, 0, 32, 2);
    PK(Wlv, Pzh, Pzl, 256, 1024, 0, 32, 3);
    PK(Wout, Poh, Pol, 256, 1024, 0, 32, 0);

    Params pr;
    pr.x = x; pr.eps = eps;
    pr.eb = eb; pr.db = db; pr.bmu = bmu; pr.blv = blv; pr.bout = bout;
    pr.Pe0h = Pe0h; pr.Pe0l = Pe0l; pr.Pe1h = Pe1h; pr.Pe1l = Pe1l;
    pr.Pe2h = Pe2h; pr.Pe2l = Pe2l; pr.Pd0h = Pd0h; pr.Pd0l = Pd0l;
    pr.Pd1h = Pd1h; pr.Pd1l = Pd1l; pr.Pd2h = Pd2h; pr.Pd2l = Pd2l;
    pr.Pzh = Pzh; pr.Pzl = Pzl; pr.Poh = Poh; pr.Pol = Pol;
    pr.Ae0 = Ae0; pr.Ae1 = Ae1; pr.Ae2 = Ae2;
    pr.Ad0 = Ad0; pr.Ad1 = Ad1; pr.Ad2 = Ad2; pr.Az = Az; pr.Ao = Ao;
    pr.ce0 = cb; pr.ce1 = cb + 64 * 1024; pr.ce2 = cb + 2 * 64 * 1024;
    pr.cd0 = cb + 3 * 64 * 1024; pr.cd1 = cb + 4 * 64 * 1024; pr.cd2 = cb + 5 * 64 * 1024;
    pr.out = out; pr.bar = bar;

    vae_persist<<<NWG, 512, 0, stream>>>(pr);
}

// Round 4
// 40475.497 us; speedup vs baseline: 1.5116x; 1.5116x over previous
//
#include <hip/hip_runtime.h>

typedef unsigned int   u32;
typedef unsigned short u16;
typedef float  f32x4  __attribute__((ext_vector_type(4)));
typedef __bf16 bf16x8 __attribute__((ext_vector_type(8)));
static_assert(sizeof(bf16x8) == 16, "bf16x8 must be 16B");

#define DEV static __device__ __forceinline__

constexpr int BN = 64;     // batch
constexpr int TN = 128;    // time steps
constexpr int DN = 256;    // input/latent dim
constexpr int HN = 1024;   // hidden
constexpr int NWG = 256;   // persistent workgroups (1 per CU)
constexpr size_t BTD = (size_t)BN * TN * DN;   // 2097152

// ---------- bf16 helpers (RNE) ----------
DEV u16 f2b(float f) {
    u32 u = __builtin_bit_cast(u32, f);
    u += 0x7fffu + ((u >> 16) & 1u);
    return (u16)(u >> 16);
}
DEV float b2f(u16 h) { u32 u = ((u32)h) << 16; return __builtin_bit_cast(float, u); }
DEV void split2(float v, u16 &hi, u16 &lo) { u16 h = f2b(v); hi = h; lo = f2b(v - b2f(h)); }
DEV bf16x8 ldfrag(const u16 *p) { return __builtin_bit_cast(bf16x8, *reinterpret_cast<const uint4 *>(p)); }
DEV float sigm(float x) { return 1.0f / (1.0f + __expf(-x)); }
#define MFMA16(a, b, c) __builtin_amdgcn_mfma_f32_16x16x32_bf16((a), (b), (c), 0, 0, 0)

// ---------- grid barrier (device-scope, cross-XCD safe) ----------
DEV void grid_barrier(u32 *bar, u32 target) {
    __syncthreads();
    if (threadIdx.x == 0) {
        __threadfence();                   // release
        __hip_atomic_fetch_add(bar, 1u, __ATOMIC_RELAXED, __HIP_MEMORY_SCOPE_AGENT);
        while (__hip_atomic_load(bar, __ATOMIC_RELAXED, __HIP_MEMORY_SCOPE_AGENT) < target)
            __builtin_amdgcn_s_sleep(2);
        __threadfence();                   // acquire
    }
    __syncthreads();
}

// ---------- zero scratch ----------
__global__ void zero_ws(uint4 *p, size_t n16) {
    size_t i = (size_t)blockIdx.x * blockDim.x + threadIdx.x;
    size_t st = (size_t)gridDim.x * blockDim.x;
    uint4 z; z.x = z.y = z.z = z.w = 0u;
    for (; i < n16; i += st) p[i] = z;
}

// ---------- prep t=0 encoder input ----------
__global__ void prep_x0(const float *__restrict__ x, u16 *__restrict__ ahi, u16 *__restrict__ alo) {
    int idx = blockIdx.x * 256 + threadIdx.x;          // 16384
    int row = idx >> 8, col = idx & 255;
    float xv = x[((size_t)row * TN) * DN + col];       // x[row][0][col]
    float xh = xv - 0.5f;                              // x0 - sigmoid(0)
    u16 h, l;
    split2(xv, h, l); ahi[row * 1536 + col] = h;        alo[row * 1536 + col] = l;
    split2(xh, h, l); ahi[row * 1536 + 256 + col] = h;  alo[row * 1536 + 256 + col] = l;
}

// ---------- pack fp32 weights -> bf16 hi/lo in MFMA fragment order ----------
// frag idx = ((nt*KTILES + kt)*64 + lane)*8 + (ko&7), lane = (n'&15) + 16*(ko>>3)
// mode 0 (Wout): n'=n                                   (nt = n>>4, 16 tiles)
// mode 1 (LSTM, n=g*1024+j): n'=(j>>2)*16 + g*4 + (j&3) (nt = j>>2, 256 tiles)
// mode 2 (W_mu,  n=c): n'=(c>>3)*16 + (c&7)             (nt = c>>3, 32 tiles)
// mode 3 (W_lv,  n=c): n'=(c>>3)*16 + 8 + (c&7)
__global__ void pack_w(const float *__restrict__ src, u16 *__restrict__ dhi, u16 *__restrict__ dlo,
                       int Nsrc, int Ksrc, int koff, int ktiles, int mode) {
    int idx = blockIdx.x * 256 + threadIdx.x;
    if (idx >= Nsrc * Ksrc) return;
    int n = idx / Ksrc, k = idx - n * Ksrc;
    float v = src[idx];
    int np;
    if (mode == 1)      { int g = n >> 10, j = n & 1023; np = ((j >> 2) << 4) + (g << 2) + (j & 3); }
    else if (mode == 2) { np = ((n >> 3) << 4) + (n & 7); }
    else if (mode == 3) { np = ((n >> 3) << 4) + 8 + (n & 7); }
    else                { np = n; }
    int kk = koff + k;
    int nt = np >> 4, nl = np & 15, kt = kk >> 5, ko = kk & 31;
    int ln = nl + ((ko >> 3) << 4);
    size_t o = (((size_t)nt * ktiles + kt) * 64 + ln) * 8 + (ko & 7);
    u16 hi = f2b(v);
    u16 lo = f2b(v - b2f(hi));
    dhi[o] = hi; dlo[o] = lo;
}

// ---------- GEMM tile: one 16-col ntile, wave=(kq,mh), K split in halves ----------
// returns reduced acc (valid for kq==0 waves)
template <int KTILES>
DEV f32x4 gemm_tile(const u16 *__restrict__ Ahi, const u16 *__restrict__ Alo,
                    const u16 *__restrict__ Whi, const u16 *__restrict__ Wlo,
                    int nt, int mh, int kq, int lane, float (*red)[64][4]) {
    constexpr int KTOT = KTILES * 32;
    constexpr int KHALF = KTILES / 2;
    const int r16 = lane & 15, kg = (lane >> 4) << 3;
    const u16 *ah = Ahi + (((mh << 4) + r16) * KTOT + kq * KHALF * 32 + kg);
    const u16 *al = Alo + (((mh << 4) + r16) * KTOT + kq * KHALF * 32 + kg);
    const u16 *wh = Whi + ((size_t)nt * KTILES + kq * KHALF) * 512 + (lane << 3);
    const u16 *wl = Wlo + ((size_t)nt * KTILES + kq * KHALF) * 512 + (lane << 3);

    f32x4 acc = {0.f, 0.f, 0.f, 0.f};
    #pragma unroll 8
    for (int kt = 0; kt < KHALF; ++kt) {
        bf16x8 bh  = ldfrag(wh + (kt << 9));
        bf16x8 bl  = ldfrag(wl + (kt << 9));
        bf16x8 a_h = ldfrag(ah + (kt << 5));
        bf16x8 a_l = ldfrag(al + (kt << 5));
        acc = MFMA16(a_h, bh, acc);
        acc = MFMA16(a_h, bl, acc);
        acc = MFMA16(a_l, bh, acc);
    }
    if (kq == 1) {
        red[mh][lane][0] = acc[0]; red[mh][lane][1] = acc[1];
        red[mh][lane][2] = acc[2]; red[mh][lane][3] = acc[3];
    }
    __syncthreads();
    if (kq == 0) {
        acc[0] += red[mh][lane][0]; acc[1] += red[mh][lane][1];
        acc[2] += red[mh][lane][2]; acc[3] += red[mh][lane][3];
    }
    return acc;
}

// ---------- one LSTM layer step: WG nt owns h-cols 4nt..4nt+3, all 4 gates ----------
template <int KTILES>
DEV void lstm_body(const u16 *__restrict__ Ahi, const u16 *__restrict__ Alo,
                   const u16 *__restrict__ Whi, const u16 *__restrict__ Wlo,
                   const float *__restrict__ bias, float *__restrict__ cbuf,
                   u16 *__restrict__ d0hi, u16 *__restrict__ d0lo, int s0,
                   u16 *__restrict__ d1hi, u16 *__restrict__ d1lo, int s1,
                   float (*red)[64][4], float (*gf)[16][16]) {
    const int nt = blockIdx.x;
    const int tid = threadIdx.x;
    const int wave = tid >> 6, lane = tid & 63;
    const int mh = wave & 3, kq = wave >> 2;

    f32x4 acc = gemm_tile<KTILES>(Ahi, Alo, Whi, Wlo, nt, mh, kq, lane, red);

    if (kq == 0) {
        const int col = lane & 15;             // g*4 + jl
        const int g = col >> 2, jl = col & 3;
        const int hcol = (nt << 2) + jl;
        const float bv = bias[(g << 10) + hcol];
        #pragma unroll
        for (int j = 0; j < 4; ++j) {
            int row = ((lane >> 4) << 2) + j;  // 0..15 within M-tile
            float v = acc[j] + bv;
            v = (g == 2) ? tanhf(v) : sigm(v);
            gf[mh][row][col] = v;
        }
    }
    __syncthreads();

    if (tid < 256) {                            // 64 rows x 4 h-cols
        int row = tid >> 2, jl = tid & 3;
        int m2 = row >> 4, r = row & 15;
        float iv = gf[m2][r][jl], fv = gf[m2][r][4 + jl];
        float gv = gf[m2][r][8 + jl], ov = gf[m2][r][12 + jl];
        int hc = (nt << 2) + jl;
        float cn = fv * cbuf[row * HN + hc] + iv * gv;
        cbuf[row * HN + hc] = cn;
        float h = ov * tanhf(cn);
        u16 hh, hl; split2(h, hh, hl);
        size_t o0 = (size_t)row * s0 + hc;
        size_t o1 = (size_t)row * s1 + hc;
        d0hi[o0] = hh; d0lo[o0] = hl;
        d1hi[o1] = hh; d1lo[o1] = hl;
    }
}

// ---------- mu / logvar / z: WG nt<32 owns dcols 8nt..8nt+7 (mu cols 0-7, lv 8-15) ----------
DEV void z_body(const u16 *__restrict__ Ahi, const u16 *__restrict__ Alo,
                const u16 *__restrict__ Whi, const u16 *__restrict__ Wlo,
                const float *__restrict__ bmu, const float *__restrict__ blv,
                const float *__restrict__ eps, int t,
                float *__restrict__ out, u16 *__restrict__ zhi, u16 *__restrict__ zlo, int sz,
                float (*red)[64][4], float (*gf)[16][16]) {
    const int nt = blockIdx.x;
    const int tid = threadIdx.x;
    const int wave = tid >> 6, lane = tid & 63;
    const int mh = wave & 3, kq = wave >> 2;

    f32x4 acc = gemm_tile<32>(Ahi, Alo, Whi, Wlo, nt, mh, kq, lane, red);

    if (kq == 0) {
        const int col = lane & 15;
        const int cl = col & 7;
        const int dcol = (nt << 3) + cl;
        const float bv = (col < 8) ? bmu[dcol] : blv[dcol];
        #pragma unroll
        for (int j = 0; j < 4; ++j) {
            int row = ((lane >> 4) << 2) + j;
            gf[mh][row][col] = fminf(20.f, fmaxf(-20.f, acc[j] + bv));
        }
    }
    __syncthreads();

    {                                           // 64 rows x 8 dcols = 512 elems
        int row = tid >> 3, cl = tid & 7;
        int m2 = row >> 4, r = row & 15;
        float mu = gf[m2][r][cl];
        float lv = gf[m2][r][8 + cl];
        int dcol = (nt << 3) + cl;
        size_t po = ((size_t)row * TN + t) * DN + dcol;
        float ev = eps[po];
        float sd = expf(0.5f * lv);
        float z = mu + ev * sd;
        out[2 * BTD + po] = mu;
        out[3 * BTD + po] = lv;
        out[4 * BTD + po] = z;
        u16 zh, zl; split2(z, zh, zl);
        zhi[(size_t)row * sz + dcol] = zh;
        zlo[(size_t)row * sz + dcol] = zl;
    }
}

// ---------- logits / rec / next-step encoder input: WG nt<16 owns dcols 16nt..+15 ----------
DEV void out_body(const u16 *__restrict__ Ahi, const u16 *__restrict__ Alo,
                  const u16 *__restrict__ Whi, const u16 *__restrict__ Wlo,
                  const float *__restrict__ bout, const float *__restrict__ x, int t,
                  float *__restrict__ out, u16 *__restrict__ e0hi, u16 *__restrict__ e0lo,
                  float (*red)[64][4]) {
    const int nt = blockIdx.x;
    const int tid = threadIdx.x;
    const int wave = tid >> 6, lane = tid & 63;
    const int mh = wave & 3, kq = wave >> 2;

    f32x4 acc = gemm_tile<32>(Ahi, Alo, Whi, Wlo, nt, mh, kq, lane, red);

    if (kq == 0) {
        const int dcol = (nt << 4) + (lane & 15);
        const float bv = bout[dcol];
        #pragma unroll
        for (int j = 0; j < 4; ++j) {
            int r = (mh << 4) + ((lane >> 4) << 2) + j;
            float lg = acc[j] + bv;
            float rc = sigm(lg);
            size_t po = ((size_t)r * TN + t) * DN + dcol;
            out[po] = rc;
            out[BTD + po] = lg;
            if (t + 1 < TN) {
                float xv = x[((size_t)r * TN + t + 1) * DN + dcol];
                float xh = xv - rc;
                u16 h, l;
                split2(xv, h, l);
                e0hi[r * 1536 + dcol] = h;       e0lo[r * 1536 + dcol] = l;
                split2(xh, h, l);
                e0hi[r * 1536 + 256 + dcol] = h; e0lo[r * 1536 + 256 + dcol] = l;
            }
        }
    }
}

// ---------- persistent all-timesteps kernel ----------
struct Params {
    const float *x, *eps;
    const float *eb, *db, *bmu, *blv, *bout;
    const u16 *Pe0h, *Pe0l, *Pe1h, *Pe1l, *Pe2h, *Pe2l;
    const u16 *Pd0h, *Pd0l, *Pd1h, *Pd1l, *Pd2h, *Pd2l;
    const u16 *Pzh, *Pzl, *Poh, *Pol;
    u16 *Ae0, *Ae1, *Ae2, *Ad0, *Ad1, *Ad2, *Az, *Ao;
    float *ce0, *ce1, *ce2, *cd0, *cd1, *cd2;
    float *out;
    u32 *bar;
};

DEV u16 *AHd(u16 *b, int W, int par) { return b + (size_t)(par * 2 + 0) * 64 * W; }
DEV u16 *ALd(u16 *b, int W, int par) { return b + (size_t)(par * 2 + 1) * 64 * W; }

__global__ __launch_bounds__(512, 2)
void vae_persist(Params pr) {
    __shared__ float red[4][64][4];   // K-half reduce (4 KiB)
    __shared__ float gf[4][16][16];   // gate/value exchange (4 KiB)
    const int wg = blockIdx.x;
    u32 seq = 0;

    for (int t = 0; t < TN; ++t) {
        const int p = t & 1, q = p ^ 1;

        // encoder L0: A=[x_t | x_hat | h0(t-1)], K=1536
        lstm_body<48>(AHd(pr.Ae0, 1536, p), ALd(pr.Ae0, 1536, p), pr.Pe0h, pr.Pe0l,
                      pr.eb, pr.ce0,
                      AHd(pr.Ae1, 2048, p), ALd(pr.Ae1, 2048, p), 2048,
                      AHd(pr.Ae0, 1536, q) + 512, ALd(pr.Ae0, 1536, q) + 512, 1536, red, gf);
        ++seq; grid_barrier(pr.bar, seq * NWG);

        // encoder L1
        lstm_body<64>(AHd(pr.Ae1, 2048, p), ALd(pr.Ae1, 2048, p), pr.Pe1h, pr.Pe1l,
                      pr.eb + 4096, pr.ce1,
                      AHd(pr.Ae2, 2048, p), ALd(pr.Ae2, 2048, p), 2048,
                      AHd(pr.Ae1, 2048, q) + 1024, ALd(pr.Ae1, 2048, q) + 1024, 2048, red, gf);
        ++seq; grid_barrier(pr.bar, seq * NWG);

        // encoder L2
        lstm_body<64>(AHd(pr.Ae2, 2048, p), ALd(pr.Ae2, 2048, p), pr.Pe2h, pr.Pe2l,
                      pr.eb + 8192, pr.ce2,
                      AHd(pr.Az, 1024, p), ALd(pr.Az, 1024, p), 1024,
                      AHd(pr.Ae2, 2048, q) + 1024, ALd(pr.Ae2, 2048, q) + 1024, 2048, red, gf);
        ++seq; grid_barrier(pr.bar, seq * NWG);

        // mu / logvar / z
        if (wg < 32)
            z_body(AHd(pr.Az, 1024, p), ALd(pr.Az, 1024, p), pr.Pzh, pr.Pzl,
                   pr.bmu, pr.blv, pr.eps, t, pr.out,
                   AHd(pr.Ad0, 1280, p), ALd(pr.Ad0, 1280, p), 1280, red, gf);
        ++seq; grid_barrier(pr.bar, seq * NWG);

        // decoder L0: A=[z | h_d0(t-1)], K=1280
        lstm_body<40>(AHd(pr.Ad0, 1280, p), ALd(pr.Ad0, 1280, p), pr.Pd0h, pr.Pd0l,
                      pr.db, pr.cd0,
                      AHd(pr.Ad1, 2048, p), ALd(pr.Ad1, 2048, p), 2048,
                      AHd(pr.Ad0, 1280, q) + 256, ALd(pr.Ad0, 1280, q) + 256, 1280, red, gf);
        ++seq; grid_barrier(pr.bar, seq * NWG);

        // decoder L1
        lstm_body<64>(AHd(pr.Ad1, 2048, p), ALd(pr.Ad1, 2048, p), pr.Pd1h, pr.Pd1l,
                      pr.db + 4096, pr.cd1,
                      AHd(pr.Ad2, 2048, p), ALd(pr.Ad2, 2048, p), 2048,
                      AHd(pr.Ad1, 2048, q) + 1024, ALd(pr.Ad1, 2048, q) + 1024, 2048, red, gf);
        ++seq; grid_barrier(pr.bar, seq * NWG);

        // decoder L2
        lstm_body<64>(AHd(pr.Ad2, 2048, p), ALd(pr.Ad2, 2048, p), pr.Pd2h, pr.Pd2l,
                      pr.db + 8192, pr.cd2,
                      AHd(pr.Ao, 1024, p), ALd(pr.Ao, 1024, p), 1024,
                      AHd(pr.Ad2, 2048, q) + 1024, ALd(pr.Ad2, 2048, q) + 1024, 2048, red, gf);
        ++seq; grid_barrier(pr.bar, seq * NWG);

        // logits / rec / next-step enc input
        if (wg < 16)
            out_body(AHd(pr.Ao, 1024, p), ALd(pr.Ao, 1024, p), pr.Poh, pr.Pol,
                     pr.bout, pr.x, t, pr.out,
                     AHd(pr.Ae0, 1536, q), ALd(pr.Ae0, 1536, q), red);
        ++seq; grid_barrier(pr.bar, seq * NWG);
    }
}

extern "C" void kernel_launch(void *const *d_in, const int *in_sizes, int n_in,
                              void *d_out, int out_size, void *d_ws, size_t ws_size,
                              hipStream_t stream) {
    (void)in_sizes; (void)n_in; (void)out_size;
    const float *x     = (const float *)d_in[0];
    const float *eps   = (const float *)d_in[1];
    const float *eWih0 = (const float *)d_in[2];
    const float *eWih  = (const float *)d_in[3];
    const float *eWhh  = (const float *)d_in[4];
    const float *eb    = (const float *)d_in[5];
    const float *Wmu   = (const float *)d_in[6];
    const float *bmu   = (const float *)d_in[7];
    const float *Wlv   = (const float *)d_in[8];
    const float *blv   = (const float *)d_in[9];
    const float *dWih0 = (const float *)d_in[10];
    const float *dWih  = (const float *)d_in[11];
    const float *dWhh  = (const float *)d_in[12];
    const float *db    = (const float *)d_in[13];
    const float *Wout  = (const float *)d_in[14];
    const float *bout  = (const float *)d_in[15];
    float *out = (float *)d_out;

    char *ws = (char *)d_ws;
    size_t cur = 0;
    auto alloc = [&](size_t bytes) -> char * {
        char *p = ws + cur;
        cur = (cur + bytes + 255) & ~(size_t)255;
        return p;
    };

    // packed weights (hi/lo bf16, MFMA fragment order) — repacked every call
    u16 *Pe0h = (u16 *)alloc((size_t)4096 * 1536 * 2), *Pe0l = (u16 *)alloc((size_t)4096 * 1536 * 2);
    u16 *Pe1h = (u16 *)alloc((size_t)4096 * 2048 * 2), *Pe1l = (u16 *)alloc((size_t)4096 * 2048 * 2);
    u16 *Pe2h = (u16 *)alloc((size_t)4096 * 2048 * 2), *Pe2l = (u16 *)alloc((size_t)4096 * 2048 * 2);
    u16 *Pd0h = (u16 *)alloc((size_t)4096 * 1280 * 2), *Pd0l = (u16 *)alloc((size_t)4096 * 1280 * 2);
    u16 *Pd1h = (u16 *)alloc((size_t)4096 * 2048 * 2), *Pd1l = (u16 *)alloc((size_t)4096 * 2048 * 2);
    u16 *Pd2h = (u16 *)alloc((size_t)4096 * 2048 * 2), *Pd2l = (u16 *)alloc((size_t)4096 * 2048 * 2);
    u16 *Pzh  = (u16 *)alloc((size_t)512 * 1024 * 2),  *Pzl  = (u16 *)alloc((size_t)512 * 1024 * 2);
    u16 *Poh  = (u16 *)alloc((size_t)256 * 1024 * 2),  *Pol  = (u16 *)alloc((size_t)256 * 1024 * 2);

    // activation buffers [parity][plane hi/lo][64][W] + cell state + barrier
    size_t zstart = cur;
    u16 *Ae0 = (u16 *)alloc((size_t)2 * 2 * 64 * 1536 * 2);
    u16 *Ae1 = (u16 *)alloc((size_t)2 * 2 * 64 * 2048 * 2);
    u16 *Ae2 = (u16 *)alloc((size_t)2 * 2 * 64 * 2048 * 2);
    u16 *Ad0 = (u16 *)alloc((size_t)2 * 2 * 64 * 1280 * 2);
    u16 *Ad1 = (u16 *)alloc((size_t)2 * 2 * 64 * 2048 * 2);
    u16 *Ad2 = (u16 *)alloc((size_t)2 * 2 * 64 * 2048 * 2);
    u16 *Az  = (u16 *)alloc((size_t)2 * 2 * 64 * 1024 * 2);
    u16 *Ao  = (u16 *)alloc((size_t)2 * 2 * 64 * 1024 * 2);
    float *cb = (float *)alloc((size_t)6 * 64 * 1024 * 4);
    u32 *bar = (u32 *)alloc(256);
    size_t zend = cur;
    if (ws_size < cur) return;   // scratch too small -> bail

    // init: zero activations/c/barrier, write t=0 encoder input
    zero_ws<<<2048, 256, 0, stream>>>((uint4 *)(ws + zstart), (zend - zstart) / 16);
    prep_x0<<<64, 256, 0, stream>>>(x, Ae0, Ae0 + (size_t)2 * 64 * 1536);

    auto PK = [&](const float *src, u16 *dh, u16 *dl, int N, int K, int koff, int kt, int mode) {
        int n = N * K;
        pack_w<<<(n + 255) / 256, 256, 0, stream>>>(src, dh, dl, N, K, koff, kt, mode);
    };
    const size_t WSTEP = (size_t)4096 * 1024;
    PK(eWih0, Pe0h, Pe0l, 4096, 512, 0, 48, 1);
    PK(eWhh,  Pe0h, Pe0l, 4096, 1024, 512, 48, 1);
    PK(eWih,  Pe1h, Pe1l, 4096, 1024, 0, 64, 1);
    PK(eWhh + WSTEP, Pe1h, Pe1l, 4096, 1024, 1024, 64, 1);
    PK(eWih + WSTEP, Pe2h, Pe2l, 4096, 1024, 0, 64, 1);
    PK(eWhh + 2 * WSTEP, Pe2h, Pe2l, 4096, 1024, 1024, 64, 1);
    PK(dWih0, Pd0h, Pd0l, 4096, 256, 0, 40, 1);
    PK(dWhh,  Pd0h, Pd0l, 4096, 1024, 256, 40, 1);
    PK(dWih,  Pd1h, Pd1l, 4096, 1024, 0, 64, 1);
    PK(dWhh + WSTEP, Pd1h, Pd1l, 4096, 1024, 1024, 64, 1);
    PK(dWih + WSTEP, Pd2h, Pd2l, 4096, 1024, 0, 64, 1);
    PK(dWhh + 2 * WSTEP, Pd2h, Pd2l, 4096, 1024, 1024, 64, 1);
    PK(Wmu, Pzh, Pzl, 256, 1024, 0, 32, 2);
    PK(Wlv, Pzh, Pzl, 256, 1024, 0, 32, 3);
    PK(Wout, Poh, Pol, 256, 1024, 0, 32, 0);

    Params pr;
    pr.x = x; pr.eps = eps;
    pr.eb = eb; pr.db = db; pr.bmu = bmu; pr.blv = blv; pr.bout = bout;
    pr.Pe0h = Pe0h; pr.Pe0l = Pe0l; pr.Pe1h = Pe1h; pr.Pe1l = Pe1l;
    pr.Pe2h = Pe2h; pr.Pe2l = Pe2l; pr.Pd0h = Pd0h; pr.Pd0l = Pd0l;
    pr.Pd1h = Pd1h; pr.Pd1l = Pd1l; pr.Pd2h = Pd2h; pr.Pd2l = Pd2l;
    pr.Pzh = Pzh; pr.Pzl = Pzl; pr.Poh = Poh; pr.Pol = Pol;
    pr.Ae0 = Ae0; pr.Ae1 = Ae1; pr.Ae2 = Ae2;
    pr.Ad0 = Ad0; pr.Ad1 = Ad1; pr.Ad2 = Ad2; pr.Az = Az; pr.Ao = Ao;
    pr.ce0 = cb; pr.ce1 = cb + 64 * 1024; pr.ce2 = cb + 2 * 64 * 1024;
    pr.cd0 = cb + 3 * 64 * 1024; pr.cd1 = cb + 4 * 64 * 1024; pr.cd2 = cb + 5 * 64 * 1024;
    pr.out = out; pr.bar = bar;

    vae_persist<<<NWG, 512, 0, stream>>>(pr);
}

// Round 5
// 32274.911 us; speedup vs baseline: 1.8956x; 1.2541x over previous
//
#include <hip/hip_runtime.h>

typedef unsigned int   u32;
typedef unsigned short u16;
typedef float  f32x4  __attribute__((ext_vector_type(4)));
typedef __bf16 bf16x8 __attribute__((ext_vector_type(8)));
static_assert(sizeof(bf16x8) == 16, "bf16x8 must be 16B");

#define DEV static __device__ __forceinline__

constexpr int BN = 64;     // batch
constexpr int TN = 128;    // time steps
constexpr int DN = 256;    // input/latent dim
constexpr int HN = 1024;   // hidden
constexpr int NWG = 256;   // persistent workgroups (1 per CU)
constexpr size_t BTD = (size_t)BN * TN * DN;   // 2097152

// ---------- bf16 helpers (RNE) ----------
DEV u16 f2b(float f) {
    u32 u = __builtin_bit_cast(u32, f);
    u += 0x7fffu + ((u >> 16) & 1u);
    return (u16)(u >> 16);
}
DEV float b2f(u16 h) { u32 u = ((u32)h) << 16; return __builtin_bit_cast(float, u); }
DEV void split2(float v, u16 &hi, u16 &lo) { u16 h = f2b(v); hi = h; lo = f2b(v - b2f(h)); }
DEV bf16x8 ldfrag(const u16 *p) { return __builtin_bit_cast(bf16x8, *reinterpret_cast<const uint4 *>(p)); }
DEV float sigm(float x) { return 1.0f / (1.0f + __expf(-x)); }
#define MFMA16(a, b, c) __builtin_amdgcn_mfma_f32_16x16x32_bf16((a), (b), (c), 0, 0, 0)

// async 16B/lane global->LDS (dest = wave-uniform base + lane*16)
DEV void gl16(const u16 *g, u16 *l) {
    __builtin_amdgcn_global_load_lds(
        (const __attribute__((address_space(1))) u32 *)g,
        (__attribute__((address_space(3))) u32 *)l, 16, 0, 0);
}

// ---------- two-level grid barrier (16 groups x 16) ----------
// bar[g*32] group counters, bar[512] root counter, bar[544] epoch.
DEV void grid_barrier(u32 *bar, u32 seq) {
    __syncthreads();
    if (threadIdx.x == 0) {
        __threadfence();                   // release
        const int g = blockIdx.x & 15;
        u32 old = __hip_atomic_fetch_add(&bar[g * 32], 1u, __ATOMIC_RELAXED, __HIP_MEMORY_SCOPE_AGENT);
        if (old == seq * 16u - 1u) {       // last of my 16-WG group
            u32 r = __hip_atomic_fetch_add(&bar[512], 1u, __ATOMIC_RELAXED, __HIP_MEMORY_SCOPE_AGENT);
            if (r == seq * 16u - 1u)       // last group
                __hip_atomic_store(&bar[544], seq, __ATOMIC_RELEASE, __HIP_MEMORY_SCOPE_AGENT);
        }
        while (__hip_atomic_load(&bar[544], __ATOMIC_RELAXED, __HIP_MEMORY_SCOPE_AGENT) < seq)
            __builtin_amdgcn_s_sleep(2);
        __threadfence();                   // acquire
    }
    __syncthreads();
}

// ---------- zero scratch ----------
__global__ void zero_ws(uint4 *p, size_t n16) {
    size_t i = (size_t)blockIdx.x * blockDim.x + threadIdx.x;
    size_t st = (size_t)gridDim.x * blockDim.x;
    uint4 z; z.x = z.y = z.z = z.w = 0u;
    for (; i < n16; i += st) p[i] = z;
}

// ---------- prep t=0 encoder input ----------
__global__ void prep_x0(const float *__restrict__ x, u16 *__restrict__ ahi, u16 *__restrict__ alo) {
    int idx = blockIdx.x * 256 + threadIdx.x;          // 16384
    int row = idx >> 8, col = idx & 255;
    float xv = x[((size_t)row * TN) * DN + col];       // x[row][0][col]
    float xh = xv - 0.5f;                              // x0 - sigmoid(0)
    u16 h, l;
    split2(xv, h, l); ahi[row * 1536 + col] = h;        alo[row * 1536 + col] = l;
    split2(xh, h, l); ahi[row * 1536 + 256 + col] = h;  alo[row * 1536 + 256 + col] = l;
}

// ---------- pack fp32 weights -> bf16 hi/lo in MFMA fragment order ----------
// frag idx = ((nt*KTILES + kt)*64 + lane)*8 + (ko&7), lane = (n'&15) + 16*(ko>>3)
// mode 0 (Wout): n'=n ; mode 1 (LSTM, n=g*1024+j): n'=(j>>2)*16+g*4+(j&3)
// mode 2 (W_mu): n'=(c>>3)*16+(c&7) ; mode 3 (W_lv): n'=(c>>3)*16+8+(c&7)
__global__ void pack_w(const float *__restrict__ src, u16 *__restrict__ dhi, u16 *__restrict__ dlo,
                       int Nsrc, int Ksrc, int koff, int ktiles, int mode) {
    int idx = blockIdx.x * 256 + threadIdx.x;
    if (idx >= Nsrc * Ksrc) return;
    int n = idx / Ksrc, k = idx - n * Ksrc;
    float v = src[idx];
    int np;
    if (mode == 1)      { int g = n >> 10, j = n & 1023; np = ((j >> 2) << 4) + (g << 2) + (j & 3); }
    else if (mode == 2) { np = ((n >> 3) << 4) + (n & 7); }
    else if (mode == 3) { np = ((n >> 3) << 4) + 8 + (n & 7); }
    else                { np = n; }
    int kk = koff + k;
    int nt = np >> 4, nl = np & 15, kt = kk >> 5, ko = kk & 31;
    int ln = nl + ((ko >> 3) << 4);
    size_t o = (((size_t)nt * ktiles + kt) * 64 + ln) * 8 + (ko & 7);
    u16 hi = f2b(v);
    u16 lo = f2b(v - b2f(hi));
    dhi[o] = hi; dlo[o] = lo;
}

#define WAITV(n) asm volatile("s_waitcnt vmcnt(" #n ")" ::: "memory")

// ---------- GEMM tile, software-pipelined via global_load_lds ring ----------
// wave=(kq,mh); per-wave private LDS ring depth 4, 4 streams x 1KB/slot.
// returns reduced acc (valid for kq==0 waves)
template <int KTILES>
DEV f32x4 gemm_tile(const u16 *__restrict__ Ahi, const u16 *__restrict__ Alo,
                    const u16 *__restrict__ Whi, const u16 *__restrict__ Wlo,
                    int nt, int mh, int kq, int wv, int lane,
                    float (*red)[64][4], u16 (*ring)[4][4][512]) {
    constexpr int KTOT = KTILES * 32;
    constexpr int KHALF = KTILES / 2;
    const int r16 = lane & 15, kg = (lane >> 4) << 3;
    const u16 *ah = Ahi + (((mh << 4) + r16) * KTOT + kq * KHALF * 32 + kg);
    const u16 *al = Alo + (((mh << 4) + r16) * KTOT + kq * KHALF * 32 + kg);
    const u16 *wh = Whi + ((size_t)nt * KTILES + kq * KHALF) * 512 + (lane << 3);
    const u16 *wl = Wlo + ((size_t)nt * KTILES + kq * KHALF) * 512 + (lane << 3);

    #define ISSUE(s) do { int _sl = (s) & 3;                  \
        gl16(wh + ((s) << 9), &ring[wv][_sl][0][0]);          \
        gl16(wl + ((s) << 9), &ring[wv][_sl][1][0]);          \
        gl16(ah + ((s) << 5), &ring[wv][_sl][2][0]);          \
        gl16(al + ((s) << 5), &ring[wv][_sl][3][0]); } while (0)

    ISSUE(0); ISSUE(1); ISSUE(2); ISSUE(3);

    f32x4 acc = {0.f, 0.f, 0.f, 0.f};
    for (int kt = 0; kt < KHALF; ++kt) {
        const int rem = KHALF - 1 - kt;
        if (rem >= 3)      WAITV(12);
        else if (rem == 2) WAITV(8);
        else if (rem == 1) WAITV(4);
        else               WAITV(0);
        const int sl = kt & 3;
        bf16x8 bh  = ldfrag(&ring[wv][sl][0][lane << 3]);
        bf16x8 bl  = ldfrag(&ring[wv][sl][1][lane << 3]);
        bf16x8 a_h = ldfrag(&ring[wv][sl][2][lane << 3]);
        bf16x8 a_l = ldfrag(&ring[wv][sl][3][lane << 3]);
        acc = MFMA16(a_h, bh, acc);
        acc = MFMA16(a_h, bl, acc);
        acc = MFMA16(a_l, bh, acc);
        if (kt + 4 < KHALF) ISSUE(kt + 4);
    }
    #undef ISSUE

    if (kq == 1) {
        red[mh][lane][0] = acc[0]; red[mh][lane][1] = acc[1];
        red[mh][lane][2] = acc[2]; red[mh][lane][3] = acc[3];
    }
    __syncthreads();
    if (kq == 0) {
        acc[0] += red[mh][lane][0]; acc[1] += red[mh][lane][1];
        acc[2] += red[mh][lane][2]; acc[3] += red[mh][lane][3];
    }
    return acc;
}

// ---------- one LSTM layer step: WG nt owns h-cols 4nt..4nt+3, all 4 gates ----------
template <int KTILES>
DEV void lstm_body(const u16 *__restrict__ Ahi, const u16 *__restrict__ Alo,
                   const u16 *__restrict__ Whi, const u16 *__restrict__ Wlo,
                   const float *__restrict__ bias, float *__restrict__ cbuf,
                   u16 *__restrict__ d0hi, u16 *__restrict__ d0lo, int s0,
                   u16 *__restrict__ d1hi, u16 *__restrict__ d1lo, int s1,
                   float (*red)[64][4], float (*gf)[16][16], u16 (*ring)[4][4][512]) {
    const int nt = blockIdx.x;
    const int tid = threadIdx.x;
    const int wave = tid >> 6, lane = tid & 63;
    const int mh = wave & 3, kq = wave >> 2;

    f32x4 acc = gemm_tile<KTILES>(Ahi, Alo, Whi, Wlo, nt, mh, kq, wave, lane, red, ring);

    if (kq == 0) {
        const int col = lane & 15;             // g*4 + jl
        const int g = col >> 2, jl = col & 3;
        const int hcol = (nt << 2) + jl;
        const float bv = bias[(g << 10) + hcol];
        #pragma unroll
        for (int j = 0; j < 4; ++j) {
            int row = ((lane >> 4) << 2) + j;  // 0..15 within M-tile
            float v = acc[j] + bv;
            v = (g == 2) ? tanhf(v) : sigm(v);
            gf[mh][row][col] = v;
        }
    }
    __syncthreads();

    if (tid < 256) {                            // 64 rows x 4 h-cols
        int row = tid >> 2, jl = tid & 3;
        int m2 = row >> 4, r = row & 15;
        float iv = gf[m2][r][jl], fv = gf[m2][r][4 + jl];
        float gv = gf[m2][r][8 + jl], ov = gf[m2][r][12 + jl];
        int hc = (nt << 2) + jl;
        float cn = fv * cbuf[row * HN + hc] + iv * gv;
        cbuf[row * HN + hc] = cn;
        float h = ov * tanhf(cn);
        u16 hh, hl; split2(h, hh, hl);
        size_t o0 = (size_t)row * s0 + hc;
        size_t o1 = (size_t)row * s1 + hc;
        d0hi[o0] = hh; d0lo[o0] = hl;
        d1hi[o1] = hh; d1lo[o1] = hl;
    }
}

// ---------- mu / logvar / z: WG nt<32 owns dcols 8nt..8nt+7 ----------
DEV void z_body(const u16 *__restrict__ Ahi, const u16 *__restrict__ Alo,
                const u16 *__restrict__ Whi, const u16 *__restrict__ Wlo,
                const float *__restrict__ bmu, const float *__restrict__ blv,
                const float *__restrict__ eps, int t,
                float *__restrict__ out, u16 *__restrict__ zhi, u16 *__restrict__ zlo, int sz,
                float (*red)[64][4], float (*gf)[16][16], u16 (*ring)[4][4][512]) {
    const int nt = blockIdx.x;
    const int tid = threadIdx.x;
    const int wave = tid >> 6, lane = tid & 63;
    const int mh = wave & 3, kq = wave >> 2;

    f32x4 acc = gemm_tile<32>(Ahi, Alo, Whi, Wlo, nt, mh, kq, wave, lane, red, ring);

    if (kq == 0) {
        const int col = lane & 15;
        const int cl = col & 7;
        const int dcol = (nt << 3) + cl;
        const float bv = (col < 8) ? bmu[dcol] : blv[dcol];
        #pragma unroll
        for (int j = 0; j < 4; ++j) {
            int row = ((lane >> 4) << 2) + j;
            gf[mh][row][col] = fminf(20.f, fmaxf(-20.f, acc[j] + bv));
        }
    }
    __syncthreads();

    {                                           // 64 rows x 8 dcols = 512 elems
        int row = tid >> 3, cl = tid & 7;
        int m2 = row >> 4, r = row & 15;
        float mu = gf[m2][r][cl];
        float lv = gf[m2][r][8 + cl];
        int dcol = (nt << 3) + cl;
        size_t po = ((size_t)row * TN + t) * DN + dcol;
        float ev = eps[po];
        float sd = expf(0.5f * lv);
        float z = mu + ev * sd;
        out[2 * BTD + po] = mu;
        out[3 * BTD + po] = lv;
        out[4 * BTD + po] = z;
        u16 zh, zl; split2(z, zh, zl);
        zhi[(size_t)row * sz + dcol] = zh;
        zlo[(size_t)row * sz + dcol] = zl;
    }
}

// ---------- logits / rec / next-step encoder input: WG nt<16 owns dcols 16nt..+15 ----------
DEV void out_body(const u16 *__restrict__ Ahi, const u16 *__restrict__ Alo,
                  const u16 *__restrict__ Whi, const u16 *__restrict__ Wlo,
                  const float *__restrict__ bout, const float *__restrict__ x, int t,
                  float *__restrict__ out, u16 *__restrict__ e0hi, u16 *__restrict__ e0lo,
                  float (*red)[64][4], u16 (*ring)[4][4][512]) {
    const int nt = blockIdx.x;
    const int tid = threadIdx.x;
    const int wave = tid >> 6, lane = tid & 63;
    const int mh = wave & 3, kq = wave >> 2;

    f32x4 acc = gemm_tile<32>(Ahi, Alo, Whi, Wlo, nt, mh, kq, wave, lane, red, ring);

    if (kq == 0) {
        const int dcol = (nt << 4) + (lane & 15);
        const float bv = bout[dcol];
        #pragma unroll
        for (int j = 0; j < 4; ++j) {
            int r = (mh << 4) + ((lane >> 4) << 2) + j;
            float lg = acc[j] + bv;
            float rc = sigm(lg);
            size_t po = ((size_t)r * TN + t) * DN + dcol;
            out[po] = rc;
            out[BTD + po] = lg;
            if (t + 1 < TN) {
                float xv = x[((size_t)r * TN + t + 1) * DN + dcol];
                float xh = xv - rc;
                u16 h, l;
                split2(xv, h, l);
                e0hi[r * 1536 + dcol] = h;       e0lo[r * 1536 + dcol] = l;
                split2(xh, h, l);
                e0hi[r * 1536 + 256 + dcol] = h; e0lo[r * 1536 + 256 + dcol] = l;
            }
        }
    }
}

// ---------- persistent all-timesteps kernel ----------
struct Params {
    const float *x, *eps;
    const float *eb, *db, *bmu, *blv, *bout;
    const u16 *Pe0h, *Pe0l, *Pe1h, *Pe1l, *Pe2h, *Pe2l;
    const u16 *Pd0h, *Pd0l, *Pd1h, *Pd1l, *Pd2h, *Pd2l;
    const u16 *Pzh, *Pzl, *Poh, *Pol;
    u16 *Ae0, *Ae1, *Ae2, *Ad0, *Ad1, *Ad2, *Az, *Ao;
    float *ce0, *ce1, *ce2, *cd0, *cd1, *cd2;
    float *out;
    u32 *bar;
};

DEV u16 *AHd(u16 *b, int W, int par) { return b + (size_t)(par * 2 + 0) * 64 * W; }
DEV u16 *ALd(u16 *b, int W, int par) { return b + (size_t)(par * 2 + 1) * 64 * W; }

__global__ __launch_bounds__(512)
void vae_persist(Params pr) {
    __shared__ u16 ring[8][4][4][512];   // per-wave gload_lds ring: 128 KiB
    __shared__ float red[4][64][4];      // K-half reduce (4 KiB)
    __shared__ float gf[4][16][16];      // gate/value exchange (4 KiB)
    const int wg = blockIdx.x;
    u32 seq = 0;

    for (int t = 0; t < TN; ++t) {
        const int p = t & 1, q = p ^ 1;

        // encoder L0: A=[x_t | x_hat | h0(t-1)], K=1536
        lstm_body<48>(AHd(pr.Ae0, 1536, p), ALd(pr.Ae0, 1536, p), pr.Pe0h, pr.Pe0l,
                      pr.eb, pr.ce0,
                      AHd(pr.Ae1, 2048, p), ALd(pr.Ae1, 2048, p), 2048,
                      AHd(pr.Ae0, 1536, q) + 512, ALd(pr.Ae0, 1536, q) + 512, 1536, red, gf, ring);
        ++seq; grid_barrier(pr.bar, seq);

        // encoder L1
        lstm_body<64>(AHd(pr.Ae1, 2048, p), ALd(pr.Ae1, 2048, p), pr.Pe1h, pr.Pe1l,
                      pr.eb + 4096, pr.ce1,
                      AHd(pr.Ae2, 2048, p), ALd(pr.Ae2, 2048, p), 2048,
                      AHd(pr.Ae1, 2048, q) + 1024, ALd(pr.Ae1, 2048, q) + 1024, 2048, red, gf, ring);
        ++seq; grid_barrier(pr.bar, seq);

        // encoder L2
        lstm_body<64>(AHd(pr.Ae2, 2048, p), ALd(pr.Ae2, 2048, p), pr.Pe2h, pr.Pe2l,
                      pr.eb + 8192, pr.ce2,
                      AHd(pr.Az, 1024, p), ALd(pr.Az, 1024, p), 1024,
                      AHd(pr.Ae2, 2048, q) + 1024, ALd(pr.Ae2, 2048, q) + 1024, 2048, red, gf, ring);
        ++seq; grid_barrier(pr.bar, seq);

        // mu / logvar / z
        if (wg < 32)
            z_body(AHd(pr.Az, 1024, p), ALd(pr.Az, 1024, p), pr.Pzh, pr.Pzl,
                   pr.bmu, pr.blv, pr.eps, t, pr.out,
                   AHd(pr.Ad0, 1280, p), ALd(pr.Ad0, 1280, p), 1280, red, gf, ring);
        ++seq; grid_barrier(pr.bar, seq);

        // decoder L0: A=[z | h_d0(t-1)], K=1280
        lstm_body<40>(AHd(pr.Ad0, 1280, p), ALd(pr.Ad0, 1280, p), pr.Pd0h, pr.Pd0l,
                      pr.db, pr.cd0,
                      AHd(pr.Ad1, 2048, p), ALd(pr.Ad1, 2048, p), 2048,
                      AHd(pr.Ad0, 1280, q) + 256, ALd(pr.Ad0, 1280, q) + 256, 1280, red, gf, ring);
        ++seq; grid_barrier(pr.bar, seq);

        // decoder L1
        lstm_body<64>(AHd(pr.Ad1, 2048, p), ALd(pr.Ad1, 2048, p), pr.Pd1h, pr.Pd1l,
                      pr.db + 4096, pr.cd1,
                      AHd(pr.Ad2, 2048, p), ALd(pr.Ad2, 2048, p), 2048,
                      AHd(pr.Ad1, 2048, q) + 1024, ALd(pr.Ad1, 2048, q) + 1024, 2048, red, gf, ring);
        ++seq; grid_barrier(pr.bar, seq);

        // decoder L2
        lstm_body<64>(AHd(pr.Ad2, 2048, p), ALd(pr.Ad2, 2048, p), pr.Pd2h, pr.Pd2l,
                      pr.db + 8192, pr.cd2,
                      AHd(pr.Ao, 1024, p), ALd(pr.Ao, 1024, p), 1024,
                      AHd(pr.Ad2, 2048, q) + 1024, ALd(pr.Ad2, 2048, q) + 1024, 2048, red, gf, ring);
        ++seq; grid_barrier(pr.bar, seq);

        // logits / rec / next-step enc input
        if (wg < 16)
            out_body(AHd(pr.Ao, 1024, p), ALd(pr.Ao, 1024, p), pr.Poh, pr.Pol,
                     pr.bout, pr.x, t, pr.out,
                     AHd(pr.Ae0, 1536, q), ALd(pr.Ae0, 1536, q), red, ring);
        ++seq; grid_barrier(pr.bar, seq);
    }
}

extern "C" void kernel_launch(void *const *d_in, const int *in_sizes, int n_in,
                              void *d_out, int out_size, void *d_ws, size_t ws_size,
                              hipStream_t stream) {
    (void)in_sizes; (void)n_in; (void)out_size;
    const float *x     = (const float *)d_in[0];
    const float *eps   = (const float *)d_in[1];
    const float *eWih0 = (const float *)d_in[2];
    const float *eWih  = (const float *)d_in[3];
    const float *eWhh  = (const float *)d_in[4];
    const float *eb    = (const float *)d_in[5];
    const float *Wmu   = (const float *)d_in[6];
    const float *bmu   = (const float *)d_in[7];
    const float *Wlv   = (const float *)d_in[8];
    const float *blv   = (const float *)d_in[9];
    const float *dWih0 = (const float *)d_in[10];
    const float *dWih  = (const float *)d_in[11];
    const float *dWhh  = (const float *)d_in[12];
    const float *db    = (const float *)d_in[13];
    const float *Wout  = (const float *)d_in[14];
    const float *bout  = (const float *)d_in[15];
    float *out = (float *)d_out;

    char *ws = (char *)d_ws;
    size_t cur = 0;
    auto alloc = [&](size_t bytes) -> char * {
        char *p = ws + cur;
        cur = (cur + bytes + 255) & ~(size_t)255;
        return p;
    };

    // packed weights (hi/lo bf16, MFMA fragment order) — repacked every call
    u16 *Pe0h = (u16 *)alloc((size_t)4096 * 1536 * 2), *Pe0l = (u16 *)alloc((size_t)4096 * 1536 * 2);
    u16 *Pe1h = (u16 *)alloc((size_t)4096 * 2048 * 2), *Pe1l = (u16 *)alloc((size_t)4096 * 2048 * 2);
    u16 *Pe2h = (u16 *)alloc((size_t)4096 * 2048 * 2), *Pe2l = (u16 *)alloc((size_t)4096 * 2048 * 2);
    u16 *Pd0h = (u16 *)alloc((size_t)4096 * 1280 * 2), *Pd0l = (u16 *)alloc((size_t)4096 * 1280 * 2);
    u16 *Pd1h = (u16 *)alloc((size_t)4096 * 2048 * 2), *Pd1l = (u16 *)alloc((size_t)4096 * 2048 * 2);
    u16 *Pd2h = (u16 *)alloc((size_t)4096 * 2048 * 2), *Pd2l = (u16 *)alloc((size_t)4096 * 2048 * 2);
    u16 *Pzh  = (u16 *)alloc((size_t)512 * 1024 * 2),  *Pzl  = (u16 *)alloc((size_t)512 * 1024 * 2);
    u16 *Poh  = (u16 *)alloc((size_t)256 * 1024 * 2),  *Pol  = (u16 *)alloc((size_t)256 * 1024 * 2);

    // activation buffers [parity][plane hi/lo][64][W] + cell state + barrier
    size_t zstart = cur;
    u16 *Ae0 = (u16 *)alloc((size_t)2 * 2 * 64 * 1536 * 2);
    u16 *Ae1 = (u16 *)alloc((size_t)2 * 2 * 64 * 2048 * 2);
    u16 *Ae2 = (u16 *)alloc((size_t)2 * 2 * 64 * 2048 * 2);
    u16 *Ad0 = (u16 *)alloc((size_t)2 * 2 * 64 * 1280 * 2);
    u16 *Ad1 = (u16 *)alloc((size_t)2 * 2 * 64 * 2048 * 2);
    u16 *Ad2 = (u16 *)alloc((size_t)2 * 2 * 64 * 2048 * 2);
    u16 *Az  = (u16 *)alloc((size_t)2 * 2 * 64 * 1024 * 2);
    u16 *Ao  = (u16 *)alloc((size_t)2 * 2 * 64 * 1024 * 2);
    float *cb = (float *)alloc((size_t)6 * 64 * 1024 * 4);
    u32 *bar = (u32 *)alloc(4096);
    size_t zend = cur;
    if (ws_size < cur) return;   // scratch too small -> bail

    // init: zero activations/c/barrier, write t=0 encoder input
    zero_ws<<<2048, 256, 0, stream>>>((uint4 *)(ws + zstart), (zend - zstart) / 16);
    prep_x0<<<64, 256, 0, stream>>>(x, Ae0, Ae0 + (size_t)2 * 64 * 1536);

    auto PK = [&](const float *src, u16 *dh, u16 *dl, int N, int K, int koff, int kt, int mode) {
        int n = N * K;
        pack_w<<<(n + 255) / 256, 256, 0, stream>>>(src, dh, dl, N, K, koff, kt, mode);
    };
    const size_t WSTEP = (size_t)4096 * 1024;
    PK(eWih0, Pe0h, Pe0l, 4096, 512, 0, 48, 1);
    PK(eWhh,  Pe0h, Pe0l, 4096, 1024, 512, 48, 1);
    PK(eWih,  Pe1h, Pe1l, 4096, 1024, 0, 64, 1);
    PK(eWhh + WSTEP, Pe1h, Pe1l, 4096, 1024, 1024, 64, 1);
    PK(eWih + WSTEP, Pe2h, Pe2l, 4096, 1024, 0, 64, 1);
    PK(eWhh + 2 * WSTEP, Pe2h, Pe2l, 4096, 1024, 1024, 64, 1);
    PK(dWih0, Pd0h, Pd0l, 4096, 256, 0, 40, 1);
    PK(dWhh,  Pd0h, Pd0l, 4096, 1024, 256, 40, 1);
    PK(dWih,  Pd1h, Pd1l, 4096, 1024, 0, 64, 1);
    PK(dWhh + WSTEP, Pd1h, Pd1l, 4096, 1024, 1024, 64, 1);
    PK(dWih + WSTEP, Pd2h, Pd2l, 4096, 1024, 0, 64, 1);
    PK(dWhh + 2 * WSTEP, Pd2h, Pd2l, 4096, 1024, 1024, 64, 1);
    PK(Wmu, Pzh, Pzl, 256, 1024, 0, 32, 2);
    PK(Wlv, Pzh, Pzl, 256, 1024, 0, 32, 3);
    PK(Wout, Poh, Pol, 256, 1024, 0, 32, 0);

    Params pr;
    pr.x = x; pr.eps = eps;
    pr.eb = eb; pr.db = db; pr.bmu = bmu; pr.blv = blv; pr.bout = bout;
    pr.Pe0h = Pe0h; pr.Pe0l = Pe0l; pr.Pe1h = Pe1h; pr.Pe1l = Pe1l;
    pr.Pe2h = Pe2h; pr.Pe2l = Pe2l; pr.Pd0h = Pd0h; pr.Pd0l = Pd0l;
    pr.Pd1h = Pd1h; pr.Pd1l = Pd1l; pr.Pd2h = Pd2h; pr.Pd2l = Pd2l;
    pr.Pzh = Pzh; pr.Pzl = Pzl; pr.Poh = Poh; pr.Pol = Pol;
    pr.Ae0 = Ae0; pr.Ae1 = Ae1; pr.Ae2 = Ae2;
    pr.Ad0 = Ad0; pr.Ad1 = Ad1; pr.Ad2 = Ad2; pr.Az = Az; pr.Ao = Ao;
    pr.ce0 = cb; pr.ce1 = cb + 64 * 1024; pr.ce2 = cb + 2 * 64 * 1024;
    pr.cd0 = cb + 3 * 64 * 1024; pr.cd1 = cb + 4 * 64 * 1024; pr.cd2 = cb + 5 * 64 * 1024;
    pr.out = out; pr.bar = bar;

    vae_persist<<<NWG, 512, 0, stream>>>(pr);
}

// Round 8
// 20755.020 us; speedup vs baseline: 2.9478x; 1.5550x over previous
//
#include <hip/hip_runtime.h>

typedef unsigned int   u32;
typedef unsigned short u16;
typedef float  f32x4  __attribute__((ext_vector_type(4)));
typedef __bf16 bf16x8 __attribute__((ext_vector_type(8)));
static_assert(sizeof(bf16x8) == 16, "bf16x8 must be 16B");

#define DEV static __device__ __forceinline__

constexpr int BN = 64;     // batch
constexpr int TN = 128;    // time steps
constexpr int DN = 256;    // input/latent dim
constexpr int HN = 1024;   // hidden
constexpr int NWG = 256;   // persistent workgroups (1 per CU)
constexpr size_t BTD = (size_t)BN * TN * DN;   // 2097152

// ---------- bf16 helpers (RNE) ----------
DEV u16 f2b(float f) {
    u32 u = __builtin_bit_cast(u32, f);
    u += 0x7fffu + ((u >> 16) & 1u);
    return (u16)(u >> 16);
}
DEV float b2f(u16 h) { u32 u = ((u32)h) << 16; return __builtin_bit_cast(float, u); }
DEV void split2(float v, u16 &hi, u16 &lo) { u16 h = f2b(v); hi = h; lo = f2b(v - b2f(h)); }
DEV bf16x8 ldfrag(const u16 *p) { return __builtin_bit_cast(bf16x8, *reinterpret_cast<const uint4 *>(p)); }
DEV float sigm(float x) { return 1.0f / (1.0f + __expf(-x)); }
#define MFMA16(a, b, c) __builtin_amdgcn_mfma_f32_16x16x32_bf16((a), (b), (c), 0, 0, 0)

// device-coherent 16-bit store (write-through to coherence point; crosses WG/XCD)
DEV void stg_sc(u16 *p, u16 v) {
    asm volatile("global_store_short %0, %1, off sc0 sc1" :: "v"(p), "v"((u32)v) : "memory");
}

// async 16B/lane global->LDS. aux: 0 = cached (read-only weights),
// 17 = SC0|SC1 device-coherent (cross-WG activations; CPol GLC=1|SCC=16)
DEV void gl16(const u16 *g, u16 *l) {
    __builtin_amdgcn_global_load_lds(
        (const __attribute__((address_space(1))) u32 *)g,
        (__attribute__((address_space(3))) u32 *)l, 16, 0, 0);
}
DEV void gl16c(const u16 *g, u16 *l) {
    __builtin_amdgcn_global_load_lds(
        (const __attribute__((address_space(1))) u32 *)g,
        (__attribute__((address_space(3))) u32 *)l, 16, 0, 17);
}

// ---------- two-level grid barrier (16 groups x 16), NO L2 flush/inv ----------
// Cross-WG data goes through sc0/sc1 ops; barrier only orders+signals.
// Bounded spin (200k polls ~= 13ms >> normal ~50us): deadlock -> garbage
// output (absmax fail) instead of GPU hang, so the bench returns evidence.
// bar[g*32] group counters, bar[512] root counter, bar[544] epoch.
DEV void grid_barrier(u32 *bar, u32 seq) {
    __syncthreads();                       // all waves drained vmcnt before s_barrier
    if (threadIdx.x == 0) {
        asm volatile("s_waitcnt vmcnt(0) lgkmcnt(0)" ::: "memory");
        const int g = blockIdx.x & 15;
        u32 old = __hip_atomic_fetch_add(&bar[g * 32], 1u, __ATOMIC_RELAXED, __HIP_MEMORY_SCOPE_AGENT);
        if (old == seq * 16u - 1u) {       // last of my 16-WG group
            u32 r = __hip_atomic_fetch_add(&bar[512], 1u, __ATOMIC_RELAXED, __HIP_MEMORY_SCOPE_AGENT);
            if (r == seq * 16u - 1u)       // last group
                __hip_atomic_store(&bar[544], seq, __ATOMIC_RELAXED, __HIP_MEMORY_SCOPE_AGENT);
        }
        u32 guard = 0;
        while (__hip_atomic_load(&bar[544], __ATOMIC_RELAXED, __HIP_MEMORY_SCOPE_AGENT) < seq) {
            __builtin_amdgcn_s_sleep(2);
            if (++guard > 200000u) break;  // diagnostic escape, never hit normally
        }
    }
    __syncthreads();
}

// ---------- zero scratch ----------
__global__ void zero_ws(uint4 *p, size_t n16) {
    size_t i = (size_t)blockIdx.x * blockDim.x + threadIdx.x;
    size_t st = (size_t)gridDim.x * blockDim.x;
    uint4 z; z.x = z.y = z.z = z.w = 0u;
    for (; i < n16; i += st) p[i] = z;
}

// ---------- prep t=0 encoder input ----------
__global__ void prep_x0(const float *__restrict__ x, u16 *__restrict__ ahi, u16 *__restrict__ alo) {
    int idx = blockIdx.x * 256 + threadIdx.x;          // 16384
    int row = idx >> 8, col = idx & 255;
    float xv = x[((size_t)row * TN) * DN + col];       // x[row][0][col]
    float xh = xv - 0.5f;                              // x0 - sigmoid(0)
    u16 h, l;
    split2(xv, h, l); ahi[row * 1536 + col] = h;        alo[row * 1536 + col] = l;
    split2(xh, h, l); ahi[row * 1536 + 256 + col] = h;  alo[row * 1536 + 256 + col] = l;
}

// ---------- pack fp32 weights -> bf16 hi/lo in MFMA fragment order ----------
// frag idx = ((nt*KTILES + kt)*64 + lane)*8 + (ko&7), lane = (n'&15) + 16*(ko>>3)
// mode 0 (Wout): n'=n ; mode 1 (LSTM, n=g*1024+j): n'=(j>>2)*16+g*4+(j&3)
// mode 2 (W_mu): n'=(c>>3)*16+(c&7) ; mode 3 (W_lv): n'=(c>>3)*16+8+(c&7)
__global__ void pack_w(const float *__restrict__ src, u16 *__restrict__ dhi, u16 *__restrict__ dlo,
                       int Nsrc, int Ksrc, int koff, int ktiles, int mode) {
    int idx = blockIdx.x * 256 + threadIdx.x;
    if (idx >= Nsrc * Ksrc) return;
    int n = idx / Ksrc, k = idx - n * Ksrc;
    float v = src[idx];
    int np;
    if (mode == 1)      { int g = n >> 10, j = n & 1023; np = ((j >> 2) << 4) + (g << 2) + (j & 3); }
    else if (mode == 2) { np = ((n >> 3) << 4) + (n & 7); }
    else if (mode == 3) { np = ((n >> 3) << 4) + 8 + (n & 7); }
    else                { np = n; }
    int kk = koff + k;
    int nt = np >> 4, nl = np & 15, kt = kk >> 5, ko = kk & 31;
    int ln = nl + ((ko >> 3) << 4);
    size_t o = (((size_t)nt * ktiles + kt) * 64 + ln) * 8 + (ko & 7);
    u16 hi = f2b(v);
    u16 lo = f2b(v - b2f(hi));
    dhi[o] = hi; dlo[o] = lo;
}

#define WAITV(n) asm volatile("s_waitcnt vmcnt(" #n ")" ::: "memory")

// ---------- GEMM tile, software-pipelined via global_load_lds ring ----------
// wave=(kq,mh); per-wave private LDS ring depth 4, 4 streams x 1KB/slot.
// W streams cached (aux 0); A streams device-coherent (aux 17).
// returns reduced acc (valid for kq==0 waves)
template <int KTILES>
DEV f32x4 gemm_tile(const u16 *__restrict__ Ahi, const u16 *__restrict__ Alo,
                    const u16 *__restrict__ Whi, const u16 *__restrict__ Wlo,
                    int nt, int mh, int kq, int wv, int lane,
                    float (*red)[64][4], u16 (*ring)[4][4][512]) {
    constexpr int KTOT = KTILES * 32;
    constexpr int KHALF = KTILES / 2;
    const int r16 = lane & 15, kg = (lane >> 4) << 3;
    const u16 *ah = Ahi + (((mh << 4) + r16) * KTOT + kq * KHALF * 32 + kg);
    const u16 *al = Alo + (((mh << 4) + r16) * KTOT + kq * KHALF * 32 + kg);
    const u16 *wh = Whi + ((size_t)nt * KTILES + kq * KHALF) * 512 + (lane << 3);
    const u16 *wl = Wlo + ((size_t)nt * KTILES + kq * KHALF) * 512 + (lane << 3);

    #define ISSUE(s) do { int _sl = (s) & 3;                  \
        gl16 (wh + ((s) << 9), &ring[wv][_sl][0][0]);         \
        gl16 (wl + ((s) << 9), &ring[wv][_sl][1][0]);         \
        gl16c(ah + ((s) << 5), &ring[wv][_sl][2][0]);         \
        gl16c(al + ((s) << 5), &ring[wv][_sl][3][0]); } while (0)

    ISSUE(0); ISSUE(1); ISSUE(2); ISSUE(3);

    f32x4 acc = {0.f, 0.f, 0.f, 0.f};
    for (int kt = 0; kt < KHALF; ++kt) {
        const int rem = KHALF - 1 - kt;
        if (rem >= 3)      WAITV(12);
        else if (rem == 2) WAITV(8);
        else if (rem == 1) WAITV(4);
        else               WAITV(0);
        const int sl = kt & 3;
        bf16x8 bh  = ldfrag(&ring[wv][sl][0][lane << 3]);
        bf16x8 bl  = ldfrag(&ring[wv][sl][1][lane << 3]);
        bf16x8 a_h = ldfrag(&ring[wv][sl][2][lane << 3]);
        bf16x8 a_l = ldfrag(&ring[wv][sl][3][lane << 3]);
        acc = MFMA16(a_h, bh, acc);
        acc = MFMA16(a_h, bl, acc);
        acc = MFMA16(a_l, bh, acc);
        if (kt + 4 < KHALF) ISSUE(kt + 4);
    }
    #undef ISSUE

    if (kq == 1) {
        red[mh][lane][0] = acc[0]; red[mh][lane][1] = acc[1];
        red[mh][lane][2] = acc[2]; red[mh][lane][3] = acc[3];
    }
    __syncthreads();
    if (kq == 0) {
        acc[0] += red[mh][lane][0]; acc[1] += red[mh][lane][1];
        acc[2] += red[mh][lane][2]; acc[3] += red[mh][lane][3];
    }
    return acc;
}

// ---------- one LSTM layer step: WG nt owns h-cols 4nt..4nt+3, all 4 gates ----------
template <int KTILES>
DEV void lstm_body(const u16 *__restrict__ Ahi, const u16 *__restrict__ Alo,
                   const u16 *__restrict__ Whi, const u16 *__restrict__ Wlo,
                   const float *__restrict__ bias, float *__restrict__ cbuf,
                   u16 *__restrict__ d0hi, u16 *__restrict__ d0lo, int s0,
                   u16 *__restrict__ d1hi, u16 *__restrict__ d1lo, int s1,
                   float (*red)[64][4], float (*gf)[16][16], u16 (*ring)[4][4][512]) {
    const int nt = blockIdx.x;
    const int tid = threadIdx.x;
    const int wave = tid >> 6, lane = tid & 63;
    const int mh = wave & 3, kq = wave >> 2;

    f32x4 acc = gemm_tile<KTILES>(Ahi, Alo, Whi, Wlo, nt, mh, kq, wave, lane, red, ring);

    if (kq == 0) {
        const int col = lane & 15;             // g*4 + jl
        const int g = col >> 2, jl = col & 3;
        const int hcol = (nt << 2) + jl;
        const float bv = bias[(g << 10) + hcol];
        #pragma unroll
        for (int j = 0; j < 4; ++j) {
            int row = ((lane >> 4) << 2) + j;  // 0..15 within M-tile
            float v = acc[j] + bv;
            v = (g == 2) ? tanhf(v) : sigm(v);
            gf[mh][row][col] = v;
        }
    }
    __syncthreads();

    if (tid < 256) {                            // 64 rows x 4 h-cols
        int row = tid >> 2, jl = tid & 3;
        int m2 = row >> 4, r = row & 15;
        float iv = gf[m2][r][jl], fv = gf[m2][r][4 + jl];
        float gv = gf[m2][r][8 + jl], ov = gf[m2][r][12 + jl];
        int hc = (nt << 2) + jl;
        float cn = fv * cbuf[row * HN + hc] + iv * gv;   // cbuf is WG-private: plain
        cbuf[row * HN + hc] = cn;
        float h = ov * tanhf(cn);
        u16 hh, hl; split2(h, hh, hl);
        size_t o0 = (size_t)row * s0 + hc;
        size_t o1 = (size_t)row * s1 + hc;
        stg_sc(d0hi + o0, hh); stg_sc(d0lo + o0, hl);    // cross-WG: coherent
        stg_sc(d1hi + o1, hh); stg_sc(d1lo + o1, hl);
    }
}

// ---------- mu / logvar / z: WG nt<32 owns dcols 8nt..8nt+7 ----------
DEV void z_body(const u16 *__restrict__ Ahi, const u16 *__restrict__ Alo,
                const u16 *__restrict__ Whi, const u16 *__restrict__ Wlo,
                const float *__restrict__ bmu, const float *__restrict__ blv,
                const float *__restrict__ eps, int t,
                float *__restrict__ out, u16 *__restrict__ zhi, u16 *__restrict__ zlo, int sz,
                float (*red)[64][4], float (*gf)[16][16], u16 (*ring)[4][4][512]) {
    const int nt = blockIdx.x;
    const int tid = threadIdx.x;
    const int wave = tid >> 6, lane = tid & 63;
    const int mh = wave & 3, kq = wave >> 2;

    f32x4 acc = gemm_tile<32>(Ahi, Alo, Whi, Wlo, nt, mh, kq, wave, lane, red, ring);

    if (kq == 0) {
        const int col = lane & 15;
        const int cl = col & 7;
        const int dcol = (nt << 3) + cl;
        const float bv = (col < 8) ? bmu[dcol] : blv[dcol];
        #pragma unroll
        for (int j = 0; j < 4; ++j) {
            int row = ((lane >> 4) << 2) + j;
            gf[mh][row][col] = fminf(20.f, fmaxf(-20.f, acc[j] + bv));
        }
    }
    __syncthreads();

    {                                           // 64 rows x 8 dcols = 512 elems
        int row = tid >> 3, cl = tid & 7;
        int m2 = row >> 4, r = row & 15;
        float mu = gf[m2][r][cl];
        float lv = gf[m2][r][8 + cl];
        int dcol = (nt << 3) + cl;
        size_t po = ((size_t)row * TN + t) * DN + dcol;
        float ev = eps[po];
        float sd = expf(0.5f * lv);
        float z = mu + ev * sd;
        out[2 * BTD + po] = mu;
        out[3 * BTD + po] = lv;
        out[4 * BTD + po] = z;
        u16 zh, zl; split2(z, zh, zl);
        stg_sc(zhi + (size_t)row * sz + dcol, zh);
        stg_sc(zlo + (size_t)row * sz + dcol, zl);
    }
}

// ---------- logits / rec / next-step encoder input: WG nt<16 owns dcols 16nt..+15 ----------
DEV void out_body(const u16 *__restrict__ Ahi, const u16 *__restrict__ Alo,
                  const u16 *__restrict__ Whi, const u16 *__restrict__ Wlo,
                  const float *__restrict__ bout, const float *__restrict__ x, int t,
                  float *__restrict__ out, u16 *__restrict__ e0hi, u16 *__restrict__ e0lo,
                  float (*red)[64][4], u16 (*ring)[4][4][512]) {
    const int nt = blockIdx.x;
    const int tid = threadIdx.x;
    const int wave = tid >> 6, lane = tid & 63;
    const int mh = wave & 3, kq = wave >> 2;

    f32x4 acc = gemm_tile<32>(Ahi, Alo, Whi, Wlo, nt, mh, kq, wave, lane, red, ring);

    if (kq == 0) {
        const int dcol = (nt << 4) + (lane & 15);
        const float bv = bout[dcol];
        #pragma unroll
        for (int j = 0; j < 4; ++j) {
            int r = (mh << 4) + ((lane >> 4) << 2) + j;
            float lg = acc[j] + bv;
            float rc = sigm(lg);
            size_t po = ((size_t)r * TN + t) * DN + dcol;
            out[po] = rc;
            out[BTD + po] = lg;
            if (t + 1 < TN) {
                float xv = x[((size_t)r * TN + t + 1) * DN + dcol];
                float xh = xv - rc;
                u16 h, l;
                split2(xv, h, l);
                stg_sc(e0hi + r * 1536 + dcol, h);
                stg_sc(e0lo + r * 1536 + dcol, l);
                split2(xh, h, l);
                stg_sc(e0hi + r * 1536 + 256 + dcol, h);
                stg_sc(e0lo + r * 1536 + 256 + dcol, l);
            }
        }
    }
}

// ---------- persistent all-timesteps kernel ----------
struct Params {
    const float *x, *eps;
    const float *eb, *db, *bmu, *blv, *bout;
    const u16 *Pe0h, *Pe0l, *Pe1h, *Pe1l, *Pe2h, *Pe2l;
    const u16 *Pd0h, *Pd0l, *Pd1h, *Pd1l, *Pd2h, *Pd2l;
    const u16 *Pzh, *Pzl, *Poh, *Pol;
    u16 *Ae0, *Ae1, *Ae2, *Ad0, *Ad1, *Ad2, *Az, *Ao;
    float *ce0, *ce1, *ce2, *cd0, *cd1, *cd2;
    float *out;
    u32 *bar;
};

DEV u16 *AHd(u16 *b, int W, int par) { return b + (size_t)(par * 2 + 0) * 64 * W; }
DEV u16 *ALd(u16 *b, int W, int par) { return b + (size_t)(par * 2 + 1) * 64 * W; }

__global__ __launch_bounds__(512)
void vae_persist(Params pr) {
    __shared__ u16 ring[8][4][4][512];   // per-wave gload_lds ring: 128 KiB
    __shared__ float red[4][64][4];      // K-half reduce (4 KiB)
    __shared__ float gf[4][16][16];      // gate/value exchange (4 KiB)
    const int wg = blockIdx.x;
    u32 seq = 0;

    for (int t = 0; t < TN; ++t) {
        const int p = t & 1, q = p ^ 1;

        // encoder L0: A=[x_t | x_hat | h0(t-1)], K=1536
        lstm_body<48>(AHd(pr.Ae0, 1536, p), ALd(pr.Ae0, 1536, p), pr.Pe0h, pr.Pe0l,
                      pr.eb, pr.ce0,
                      AHd(pr.Ae1, 2048, p), ALd(pr.Ae1, 2048, p), 2048,
                      AHd(pr.Ae0, 1536, q) + 512, ALd(pr.Ae0, 1536, q) + 512, 1536, red, gf, ring);
        ++seq; grid_barrier(pr.bar, seq);

        // encoder L1
        lstm_body<64>(AHd(pr.Ae1, 2048, p), ALd(pr.Ae1, 2048, p), pr.Pe1h, pr.Pe1l,
                      pr.eb + 4096, pr.ce1,
                      AHd(pr.Ae2, 2048, p), ALd(pr.Ae2, 2048, p), 2048,
                      AHd(pr.Ae1, 2048, q) + 1024, ALd(pr.Ae1, 2048, q) + 1024, 2048, red, gf, ring);
        ++seq; grid_barrier(pr.bar, seq);

        // encoder L2
        lstm_body<64>(AHd(pr.Ae2, 2048, p), ALd(pr.Ae2, 2048, p), pr.Pe2h, pr.Pe2l,
                      pr.eb + 8192, pr.ce2,
                      AHd(pr.Az, 1024, p), ALd(pr.Az, 1024, p), 1024,
                      AHd(pr.Ae2, 2048, q) + 1024, ALd(pr.Ae2, 2048, q) + 1024, 2048, red, gf, ring);
        ++seq; grid_barrier(pr.bar, seq);

        // mu / logvar / z
        if (wg < 32)
            z_body(AHd(pr.Az, 1024, p), ALd(pr.Az, 1024, p), pr.Pzh, pr.Pzl,
                   pr.bmu, pr.blv, pr.eps, t, pr.out,
                   AHd(pr.Ad0, 1280, p), ALd(pr.Ad0, 1280, p), 1280, red, gf, ring);
        ++seq; grid_barrier(pr.bar, seq);

        // decoder L0: A=[z | h_d0(t-1)], K=1280
        lstm_body<40>(AHd(pr.Ad0, 1280, p), ALd(pr.Ad0, 1280, p), pr.Pd0h, pr.Pd0l,
                      pr.db, pr.cd0,
                      AHd(pr.Ad1, 2048, p), ALd(pr.Ad1, 2048, p), 2048,
                      AHd(pr.Ad0, 1280, q) + 256, ALd(pr.Ad0, 1280, q) + 256, 1280, red, gf, ring);
        ++seq; grid_barrier(pr.bar, seq);

        // decoder L1
        lstm_body<64>(AHd(pr.Ad1, 2048, p), ALd(pr.Ad1, 2048, p), pr.Pd1h, pr.Pd1l,
                      pr.db + 4096, pr.cd1,
                      AHd(pr.Ad2, 2048, p), ALd(pr.Ad2, 2048, p), 2048,
                      AHd(pr.Ad1, 2048, q) + 1024, ALd(pr.Ad1, 2048, q) + 1024, 2048, red, gf, ring);
        ++seq; grid_barrier(pr.bar, seq);

        // decoder L2
        lstm_body<64>(AHd(pr.Ad2, 2048, p), ALd(pr.Ad2, 2048, p), pr.Pd2h, pr.Pd2l,
                      pr.db + 8192, pr.cd2,
                      AHd(pr.Ao, 1024, p), ALd(pr.Ao, 1024, p), 1024,
                      AHd(pr.Ad2, 2048, q) + 1024, ALd(pr.Ad2, 2048, q) + 1024, 2048, red, gf, ring);
        ++seq; grid_barrier(pr.bar, seq);

        // logits / rec / next-step enc input
        if (wg < 16)
            out_body(AHd(pr.Ao, 1024, p), ALd(pr.Ao, 1024, p), pr.Poh, pr.Pol,
                     pr.bout, pr.x, t, pr.out,
                     AHd(pr.Ae0, 1536, q), ALd(pr.Ae0, 1536, q), red, ring);
        ++seq; grid_barrier(pr.bar, seq);
    }
}

extern "C" void kernel_launch(void *const *d_in, const int *in_sizes, int n_in,
                              void *d_out, int out_size, void *d_ws, size_t ws_size,
                              hipStream_t stream) {
    (void)in_sizes; (void)n_in; (void)out_size;
    const float *x     = (const float *)d_in[0];
    const float *eps   = (const float *)d_in[1];
    const float *eWih0 = (const float *)d_in[2];
    const float *eWih  = (const float *)d_in[3];
    const float *eWhh  = (const float *)d_in[4];
    const float *eb    = (const float *)d_in[5];
    const float *Wmu   = (const float *)d_in[6];
    const float *bmu   = (const float *)d_in[7];
    const float *Wlv   = (const float *)d_in[8];
    const float *blv   = (const float *)d_in[9];
    const float *dWih0 = (const float *)d_in[10];
    const float *dWih  = (const float *)d_in[11];
    const float *dWhh  = (const float *)d_in[12];
    const float *db    = (const float *)d_in[13];
    const float *Wout  = (const float *)d_in[14];
    const float *bout  = (const float *)d_in[15];
    float *out = (float *)d_out;

    char *ws = (char *)d_ws;
    size_t cur = 0;
    auto alloc = [&](size_t bytes) -> char * {
        char *p = ws + cur;
        cur = (cur + bytes + 255) & ~(size_t)255;
        return p;
    };

    // packed weights (hi/lo bf16, MFMA fragment order) — repacked every call
    u16 *Pe0h = (u16 *)alloc((size_t)4096 * 1536 * 2), *Pe0l = (u16 *)alloc((size_t)4096 * 1536 * 2);
    u16 *Pe1h = (u16 *)alloc((size_t)4096 * 2048 * 2), *Pe1l = (u16 *)alloc((size_t)4096 * 2048 * 2);
    u16 *Pe2h = (u16 *)alloc((size_t)4096 * 2048 * 2), *Pe2l = (u16 *)alloc((size_t)4096 * 2048 * 2);
    u16 *Pd0h = (u16 *)alloc((size_t)4096 * 1280 * 2), *Pd0l = (u16 *)alloc((size_t)4096 * 1280 * 2);
    u16 *Pd1h = (u16 *)alloc((size_t)4096 * 2048 * 2), *Pd1l = (u16 *)alloc((size_t)4096 * 2048 * 2);
    u16 *Pd2h = (u16 *)alloc((size_t)4096 * 2048 * 2), *Pd2l = (u16 *)alloc((size_t)4096 * 2048 * 2);
    u16 *Pzh  = (u16 *)alloc((size_t)512 * 1024 * 2),  *Pzl  = (u16 *)alloc((size_t)512 * 1024 * 2);
    u16 *Poh  = (u16 *)alloc((size_t)256 * 1024 * 2),  *Pol  = (u16 *)alloc((size_t)256 * 1024 * 2);

    // activation buffers [parity][plane hi/lo][64][W] + cell state + barrier
    size_t zstart = cur;
    u16 *Ae0 = (u16 *)alloc((size_t)2 * 2 * 64 * 1536 * 2);
    u16 *Ae1 = (u16 *)alloc((size_t)2 * 2 * 64 * 2048 * 2);
    u16 *Ae2 = (u16 *)alloc((size_t)2 * 2 * 64 * 2048 * 2);
    u16 *Ad0 = (u16 *)alloc((size_t)2 * 2 * 64 * 1280 * 2);
    u16 *Ad1 = (u16 *)alloc((size_t)2 * 2 * 64 * 2048 * 2);
    u16 *Ad2 = (u16 *)alloc((size_t)2 * 2 * 64 * 2048 * 2);
    u16 *Az  = (u16 *)alloc((size_t)2 * 2 * 64 * 1024 * 2);
    u16 *Ao  = (u16 *)alloc((size_t)2 * 2 * 64 * 1024 * 2);
    float *cb = (float *)alloc((size_t)6 * 64 * 1024 * 4);
    u32 *bar = (u32 *)alloc(4096);
    size_t zend = cur;
    if (ws_size < cur) return;   // scratch too small -> bail

    // init: zero activations/c/barrier, write t=0 encoder input
    zero_ws<<<2048, 256, 0, stream>>>((uint4 *)(ws + zstart), (zend - zstart) / 16);
    prep_x0<<<64, 256, 0, stream>>>(x, Ae0, Ae0 + (size_t)2 * 64 * 1536);

    auto PK = [&](const float *src, u16 *dh, u16 *dl, int N, int K, int koff, int kt, int mode) {
        int n = N * K;
        pack_w<<<(n + 255) / 256, 256, 0, stream>>>(src, dh, dl, N, K, koff, kt, mode);
    };
    const size_t WSTEP = (size_t)4096 * 1024;
    PK(eWih0, Pe0h, Pe0l, 4096, 512, 0, 48, 1);
    PK(eWhh,  Pe0h, Pe0l, 4096, 1024, 512, 48, 1);
    PK(eWih,  Pe1h, Pe1l, 4096, 1024, 0, 64, 1);
    PK(eWhh + WSTEP, Pe1h, Pe1l, 4096, 1024, 1024, 64, 1);
    PK(eWih + WSTEP, Pe2h, Pe2l, 4096, 1024, 0, 64, 1);
    PK(eWhh + 2 * WSTEP, Pe2h, Pe2l, 4096, 1024, 1024, 64, 1);
    PK(dWih0, Pd0h, Pd0l, 4096, 256, 0, 40, 1);
    PK(dWhh,  Pd0h, Pd0l, 4096, 1024, 256, 40, 1);
    PK(dWih,  Pd1h, Pd1l, 4096, 1024, 0, 64, 1);
    PK(dWhh + WSTEP, Pd1h, Pd1l, 4096, 1024, 1024, 64, 1);
    PK(dWih + WSTEP, Pd2h, Pd2l, 4096, 1024, 0, 64, 1);
    PK(dWhh + 2 * WSTEP, Pd2h, Pd2l, 4096, 1024, 1024, 64, 1);
    PK(Wmu, Pzh, Pzl, 256, 1024, 0, 32, 2);
    PK(Wlv, Pzh, Pzl, 256, 1024, 0, 32, 3);
    PK(Wout, Poh, Pol, 256, 1024, 0, 32, 0);

    Params pr;
    pr.x = x; pr.eps = eps;
    pr.eb = eb; pr.db = db; pr.bmu = bmu; pr.blv = blv; pr.bout = bout;
    pr.Pe0h = Pe0h; pr.Pe0l = Pe0l; pr.Pe1h = Pe1h; pr.Pe1l = Pe1l;
    pr.Pe2h = Pe2h; pr.Pe2l = Pe2l; pr.Pd0h = Pd0h; pr.Pd0l = Pd0l;
    pr.Pd1h = Pd1h; pr.Pd1l = Pd1l; pr.Pd2h = Pd2h; pr.Pd2l = Pd2l;
    pr.Pzh = Pzh; pr.Pzl = Pzl; pr.Poh = Poh; pr.Pol = Pol;
    pr.Ae0 = Ae0; pr.Ae1 = Ae1; pr.Ae2 = Ae2;
    pr.Ad0 = Ad0; pr.Ad1 = Ad1; pr.Ad2 = Ad2; pr.Az = Az; pr.Ao = Ao;
    pr.ce0 = cb; pr.ce1 = cb + 64 * 1024; pr.ce2 = cb + 2 * 64 * 1024;
    pr.cd0 = cb + 3 * 64 * 1024; pr.cd1 = cb + 4 * 64 * 1024; pr.cd2 = cb + 5 * 64 * 1024;
    pr.out = out; pr.bar = bar;

    vae_persist<<<NWG, 512, 0, stream>>>(pr);
}